// Round 6
// baseline (1080.192 us; speedup 1.0000x reference)
//
#include <hip/hip_runtime.h>
#include <hip/hip_bf16.h>
#include <math.h>

#define N_NODES 100000
#define N_EDGES 1000000
#define IN_DIM 128
#define HID 64
#define NET 4
#define STEPS 5
#define G_GRAPHS 128
#define LBL 10
#define NGRP 6250        // N_NODES / 16 (exact)
#define NGRP_PAD 6256    // padded to multiple of 4 (each mm block covers 4 groups)

typedef __attribute__((ext_vector_type(8))) short short8;
typedef __attribute__((ext_vector_type(4))) float f32x4;
typedef unsigned short ushort_t;

__device__ inline ushort_t f2bf(float v) {
    __hip_bfloat16 b = __float2bfloat16(v);
    return __builtin_bit_cast(ushort_t, b);
}
__device__ inline float bf2f(ushort_t u) {
    __hip_bfloat16 b = __builtin_bit_cast(__hip_bfloat16, u);
    return __bfloat162float(b);
}

// AH layout: [group][32 blocks][16 rows(u)][8 elems(j)] shorts.
// blocks 0-7: a-hi, 8-15: h-hi, 16-23: a-lo, 24-31: h-lo.  group stride = 4096 shorts.

// ---------------- pack B1: We -> [6 slices][16 ct][4 g][16 u][8 j] bf16 ----------------
__global__ void k_pack_b1(const float* __restrict__ We, const float* __restrict__ be,
                          ushort_t* __restrict__ B1, float* __restrict__ bs1) {
    int idx = blockIdx.x * blockDim.x + threadIdx.x;
    if (idx >= 6 * 16 * 4 * 16 * 8) return;
    int j = idx & 7, u = (idx >> 3) & 15, g = (idx >> 7) & 3, ct = (idx >> 9) & 15, s = idx >> 13;
    int m = ct * 16 + u;
    int t = m >> 6, o = m & 63;
    int sk = (s < 2) ? s : (s < 4) ? (s - 2) : (s - 4);
    int k = sk * 32 + g * 8 + j;
    float val = We[t * 4096 + o * 64 + k];
    ushort_t hi = f2bf(val);
    B1[idx] = (s < 4) ? hi : f2bf(val - bf2f(hi));
    if (s == 0 && g == 0 && j == 0) bs1[m] = be[t * 64 + o];
}

// ---------------- pack B2: GRU fused weight -> [12][16][4][16][8] bf16 ----------------
__global__ void k_pack_b2(const float* __restrict__ W_ih, const float* __restrict__ b_ih,
                          const float* __restrict__ W_hh, const float* __restrict__ b_hh,
                          ushort_t* __restrict__ B2, float* __restrict__ bg2) {
    int idx = blockIdx.x * blockDim.x + threadIdx.x;
    if (idx >= 12 * 16 * 4 * 16 * 8) return;
    int j = idx & 7, u = (idx >> 3) & 15, g = (idx >> 7) & 3, ct = (idx >> 9) & 15, s = idx >> 13;
    int m = ct * 16 + u;
    int q = m >> 6, gate = (m >> 4) & 3, c = q * 16 + (m & 15);
    int k = (s & 3) * 32 + g * 8 + j;
    float val;
    if (gate == 0)      { int jr = c;        val = (k < 64) ? W_ih[jr * 64 + k] : W_hh[jr * 64 + k - 64]; }
    else if (gate == 1) { int jr = 64 + c;   val = (k < 64) ? W_ih[jr * 64 + k] : W_hh[jr * 64 + k - 64]; }
    else if (gate == 2) { int jr = 128 + c;  val = (k < 64) ? W_ih[jr * 64 + k] : 0.f; }
    else                { int jr = 128 + c;  val = (k < 64) ? 0.f : W_hh[jr * 64 + k - 64]; }
    ushort_t hi = f2bf(val);
    B2[idx] = (s < 8) ? hi : f2bf(val - bf2f(hi));
    if (s == 0 && g == 0 && j == 0) {
        float bv;
        if (gate == 0)      bv = b_ih[c] + b_hh[c];
        else if (gate == 1) bv = b_ih[64 + c] + b_hh[64 + c];
        else if (gate == 2) bv = b_ih[128 + c];
        else                bv = b_hh[128 + c];
        bg2[m] = bv;
    }
}

// ---------------- pack BIN: W_in -> [12 slices][4 ct][64 lane][8 j] bf16 ----------------
__global__ void k_pack_bin(const float* __restrict__ W_in, ushort_t* __restrict__ BIN) {
    int idx = blockIdx.x * blockDim.x + threadIdx.x; // 12*4*64*8 = 24576
    if (idx >= 24576) return;
    int j = idx & 7, lu = (idx >> 3) & 63, ct = (idx >> 9) & 3, s = idx >> 11;
    int g = lu >> 4, u = lu & 15;
    int m = ct * 16 + u;
    int k = (s & 3) * 32 + g * 8 + j;
    float val = W_in[m * 128 + k];
    ushort_t hi = f2bf(val);
    BIN[idx] = (s < 8) ? hi : f2bf(val - bf2f(hi));
}

// ---------------- h0 = x @ W_in.T + b_in via MFMA ----------------
__global__ __launch_bounds__(256) void k_linear_in(const float* __restrict__ x,
        const ushort_t* __restrict__ BIN, const float* __restrict__ b_in,
        ushort_t* __restrict__ AH) {
    __shared__ float hlds[4][16 * 68];
    int tid = threadIdx.x;
    int lane = tid & 63, wp = tid >> 6;
    int g = lane >> 4, u = lane & 15;
    int grp = blockIdx.x * 4 + wp;
    bool ok = grp < NGRP;
    int row = ok ? (grp * 16 + u) : 0;
    short8 xhi[4], xlo[4];
    #pragma unroll
    for (int ks = 0; ks < 4; ++ks) {
        const float* xp = &x[(size_t)row * 128 + ks * 32 + g * 8];
        float4 v0 = ok ? *(const float4*)xp : make_float4(0.f, 0.f, 0.f, 0.f);
        float4 v1 = ok ? *(const float4*)(xp + 4) : make_float4(0.f, 0.f, 0.f, 0.f);
        float vv[8] = {v0.x, v0.y, v0.z, v0.w, v1.x, v1.y, v1.z, v1.w};
        #pragma unroll
        for (int j = 0; j < 8; ++j) {
            ushort_t hh = f2bf(vv[j]);
            xhi[ks][j] = (short)hh;
            xlo[ks][j] = (short)f2bf(vv[j] - bf2f(hh));
        }
    }
    f32x4 zero = {0.f, 0.f, 0.f, 0.f};
    f32x4 acc[4] = {zero, zero, zero, zero};
    #pragma unroll
    for (int s = 0; s < 12; ++s) {
        int ks = s & 3;
        short8 af = (s < 4) ? xhi[ks] : (s < 8) ? xlo[ks] : xhi[ks];
        #pragma unroll
        for (int ct = 0; ct < 4; ++ct) {
            short8 bf = *(const short8*)&BIN[((size_t)(s * 4 + ct) * 64 + lane) * 8];
            acc[ct] = __builtin_amdgcn_mfma_f32_16x16x32_bf16(af, bf, acc[ct], 0, 0, 0);
        }
    }
    #pragma unroll
    for (int ct = 0; ct < 4; ++ct) {
        float bo = b_in[ct * 16 + u];
        #pragma unroll
        for (int j = 0; j < 4; ++j)
            hlds[wp][(g * 4 + j) * 68 + ct * 16 + u] = acc[ct][j] + bo;
    }
    __syncthreads();
    #pragma unroll
    for (int k = 0; k < 4; ++k) {
        int bi = g + 4 * k;      // 0..15
        short8 ov;
        #pragma unroll
        for (int j = 0; j < 8; ++j) {
            float v = hlds[wp][u * 68 + (bi & 7) * 8 + j];
            ushort_t hh = f2bf(v);
            ov[j] = (bi < 8) ? (short)hh : (short)f2bf(v - bf2f(hh));
        }
        int blk = (bi < 8) ? (8 + bi) : (24 + (bi - 8));
        if (ok) *(short8*)&AH[((size_t)grp * 32 + blk) * 128 + u * 8] = ov;
    }
}

// ---------------- CSR build (once per call) ----------------
__global__ void k_hist(const int* __restrict__ dst, int* __restrict__ deg) {
    int e = blockIdx.x * blockDim.x + threadIdx.x;
    if (e < N_EDGES) atomicAdd(&deg[dst[e]], 1);
}

__global__ __launch_bounds__(256) void k_scan1(const int* __restrict__ deg,
        int* __restrict__ ex, int* __restrict__ bsum, int n) {
    __shared__ int ts[256];
    int base = blockIdx.x * 1024;
    int vals[4]; int s = 0;
    #pragma unroll
    for (int i = 0; i < 4; ++i) {
        int idx = base + threadIdx.x * 4 + i;
        vals[i] = (idx < n) ? deg[idx] : 0;
        s += vals[i];
    }
    ts[threadIdx.x] = s;
    __syncthreads();
    for (int off = 1; off < 256; off <<= 1) {
        int v = (threadIdx.x >= off) ? ts[threadIdx.x - off] : 0;
        __syncthreads();
        ts[threadIdx.x] += v;
        __syncthreads();
    }
    int run = (threadIdx.x == 0) ? 0 : ts[threadIdx.x - 1];
    #pragma unroll
    for (int i = 0; i < 4; ++i) {
        int idx = base + threadIdx.x * 4 + i;
        if (idx < n) ex[idx] = run;
        run += vals[i];
    }
    if (threadIdx.x == 255) bsum[blockIdx.x] = ts[255];
}

__global__ void k_scan2(int* bsum, int nb, int* row_ptr_end) {
    if (threadIdx.x == 0 && blockIdx.x == 0) {
        int run = 0;
        for (int i = 0; i < nb; ++i) { int t = bsum[i]; bsum[i] = run; run += t; }
        *row_ptr_end = run;
    }
}

__global__ void k_scan3(int* __restrict__ row_ptr, int* __restrict__ cursor,
                        const int* __restrict__ bsum, int n) {
    int i = blockIdx.x * blockDim.x + threadIdx.x;
    if (i < n) {
        int v = row_ptr[i] + bsum[i >> 10];
        row_ptr[i] = v;
        cursor[i] = v;
    }
}

__global__ void k_fill(const int* __restrict__ src, const int* __restrict__ dst,
                       const int* __restrict__ et, int* __restrict__ cursor,
                       int* __restrict__ adj) {
    int e = blockIdx.x * blockDim.x + threadIdx.x;
    if (e < N_EDGES) {
        int d = dst[e];
        int p = atomicAdd(&cursor[d], 1);
        adj[p] = src[e] | (et[e] << 20);
    }
}

// ---------------- GEMM1: trans[N,256](bf16) = split3(h) x B1 ----------------
// 64 rows/block (4 groups), 8 waves = (rp 0..1) x (q 0..3); wave tile 32x64, acc[2][4]
__global__ __launch_bounds__(512, 6) void k_mm1(const ushort_t* __restrict__ AH,
        const ushort_t* __restrict__ B1, const float* __restrict__ bs1,
        ushort_t* __restrict__ trans) {
    __shared__ ushort_t lds[64 * 264];   // epilogue assembly
    int tid = threadIdx.x;
    int lane = tid & 63, wp = tid >> 6;
    int q = wp & 3, rp = wp >> 2;        // rp 0..1
    int g = lane >> 4, u = lane & 15;
    int n0 = blockIdx.x * 64;
    size_t grpbase = (size_t)(blockIdx.x * 4 + rp * 2);
    f32x4 zero = {0.f, 0.f, 0.f, 0.f};
    f32x4 acc[2][4];
    #pragma unroll
    for (int i = 0; i < 2; ++i)
        #pragma unroll
        for (int j = 0; j < 4; ++j) acc[i][j] = zero;
    const int bb1[6] = {8, 12, 24, 28, 8, 12};   // h-hi, h-lo, h-hi blocks
    #pragma unroll
    for (int s = 0; s < 6; ++s) {
        short8 bfr[4], afr[2];
        #pragma unroll
        for (int ct = 0; ct < 4; ++ct)
            bfr[ct] = *(const short8*)&B1[((size_t)(s * 16 + q * 4 + ct) * 64 + g * 16 + u) * 8];
        #pragma unroll
        for (int rt = 0; rt < 2; ++rt)
            afr[rt] = *(const short8*)&AH[((grpbase + rt) * 32 + bb1[s] + g) * 128 + u * 8];
        #pragma unroll
        for (int rt = 0; rt < 2; ++rt)
            #pragma unroll
            for (int ct = 0; ct < 4; ++ct)
                acc[rt][ct] = __builtin_amdgcn_mfma_f32_16x16x32_bf16(afr[rt], bfr[ct], acc[rt][ct], 0, 0, 0);
    }
    float bsv[4];
    #pragma unroll
    for (int ct = 0; ct < 4; ++ct) bsv[ct] = bs1[q * 64 + ct * 16 + u];
    #pragma unroll
    for (int rt = 0; rt < 2; ++rt)
        #pragma unroll
        for (int ct = 0; ct < 4; ++ct)
            #pragma unroll
            for (int j = 0; j < 4; ++j) {
                int rl = rp * 32 + rt * 16 + g * 4 + j;
                lds[rl * 264 + q * 64 + ct * 16 + u] = f2bf(acc[rt][ct][j] + bsv[ct]);
            }
    __syncthreads();
    int rl = tid >> 3, seg = tid & 7;
    int n = n0 + rl;
    if (n < N_NODES) {
        #pragma unroll
        for (int i = 0; i < 4; ++i) {
            short8 v = *(const short8*)&lds[rl * 264 + seg * 32 + i * 8];
            *(short8*)&trans[(size_t)n * 256 + seg * 32 + i * 8] = v;
        }
    }
}

// ---------------- GEMM2 + GRU: h = GRU(a,h) in-place in AH ----------------
// 64 rows/block (4 groups), 8 waves = (rp 0..1) x (q 0..3); wave tile 32x64, acc[2][4]
__global__ __launch_bounds__(512, 6) void k_mm2(ushort_t* __restrict__ AH,
        const ushort_t* __restrict__ B2, const float* __restrict__ bg2) {
    __shared__ ushort_t hl[64 * 136];    // h-out split: [row][hi 0..63 | lo 64..127 | pad]
    int tid = threadIdx.x;
    int lane = tid & 63, wp = tid >> 6;
    int q = wp & 3, rp = wp >> 2;        // rp 0..1
    int g = lane >> 4, u = lane & 15;
    size_t grpbase = (size_t)(blockIdx.x * 4 + rp * 2);
    f32x4 zero = {0.f, 0.f, 0.f, 0.f};
    f32x4 acc[2][4];
    #pragma unroll
    for (int i = 0; i < 2; ++i)
        #pragma unroll
        for (int j = 0; j < 4; ++j) acc[i][j] = zero;
    const int bb2[12] = {0, 4, 8, 12, 16, 20, 24, 28, 0, 4, 8, 12};
    #pragma unroll
    for (int s = 0; s < 12; ++s) {
        short8 bfr[4], afr[2];
        #pragma unroll
        for (int ct = 0; ct < 4; ++ct)
            bfr[ct] = *(const short8*)&B2[((size_t)(s * 16 + q * 4 + ct) * 64 + g * 16 + u) * 8];
        #pragma unroll
        for (int rt = 0; rt < 2; ++rt)
            afr[rt] = *(const short8*)&AH[((grpbase + rt) * 32 + bb2[s] + g) * 128 + u * 8];
        #pragma unroll
        for (int rt = 0; rt < 2; ++rt)
            #pragma unroll
            for (int ct = 0; ct < 4; ++ct)
                acc[rt][ct] = __builtin_amdgcn_mfma_f32_16x16x32_bf16(afr[rt], bfr[ct], acc[rt][ct], 0, 0, 0);
    }
    float bgv[4];
    #pragma unroll
    for (int ct = 0; ct < 4; ++ct) bgv[ct] = bg2[q * 64 + ct * 16 + u];
    int hid = q * 16 + u;
    int bhi = 8 + (hid >> 3), blo = 24 + (hid >> 3), el = hid & 7;
    #pragma unroll
    for (int rt = 0; rt < 2; ++rt) {
        size_t rbase = (grpbase + rt) * 4096;
        float ho[4];
        #pragma unroll
        for (int j = 0; j < 4; ++j) {
            int uu = g * 4 + j;
            ho[j] = bf2f(AH[rbase + bhi * 128 + uu * 8 + el])
                  + bf2f(AH[rbase + blo * 128 + uu * 8 + el]);
        }
        #pragma unroll
        for (int j = 0; j < 4; ++j) {
            float rs  = acc[rt][0][j] + bgv[0];
            float zs  = acc[rt][1][j] + bgv[1];
            float inn = acc[rt][2][j] + bgv[2];
            float hnn = acc[rt][3][j] + bgv[3];
            float r = 1.f / (1.f + __expf(-rs));
            float z = 1.f / (1.f + __expf(-zs));
            float t = inn + r * hnn;
            float e2 = __expf(2.f * t);
            float nn = 1.f - 2.f / (e2 + 1.f);   // tanh(t), NaN-free
            float hnew = (1.f - z) * nn + z * ho[j];
            int rl = rp * 32 + rt * 16 + g * 4 + j;
            ushort_t hh = f2bf(hnew);
            hl[rl * 136 + hid] = hh;
            hl[rl * 136 + 64 + hid] = f2bf(hnew - bf2f(hh));
        }
    }
    __syncthreads();
    // pack-out: 4 groups x 16 blocks x 16 u = 1024 short8 chunks, coalesced
    #pragma unroll
    for (int k = 0; k < 2; ++k) {
        int c = tid + k * 512;
        int gi = c >> 8, r = c & 255, bi = r >> 4, uu = r & 15;
        int row = gi * 16 + uu;
        int lofs = row * 136 + (bi < 8 ? bi * 8 : 64 + (bi - 8) * 8);
        short8 v = *(const short8*)&hl[lofs];
        int blk = (bi < 8) ? (8 + bi) : (16 + bi);   // h-hi 8..15, h-lo 24..31
        *(short8*)&AH[((size_t)(blockIdx.x * 4 + gi) * 32 + blk) * 128 + uu * 8] = v;
    }
}

// ---------------- aggregation via CSR; 1 node per wave, unroll-8 MLP ----------------
__global__ __launch_bounds__(1024) void k_aggregate(const int* __restrict__ row_ptr,
        const int* __restrict__ adj, const ushort_t* __restrict__ trans,
        ushort_t* __restrict__ AH) {
    __shared__ float alds[16 * 72];
    int w = threadIdx.x >> 6, lane = threadIdx.x & 63;
    int grp = blockIdx.x;
    int n = grp * 16 + w;
    int beg = row_ptr[n], end = row_ptr[n + 1];
    float a0 = 0.f, a1 = 0.f, a2 = 0.f, a3 = 0.f;
    int i = beg;
    for (; i + 8 <= end; i += 8) {
        int pk[8];
        #pragma unroll
        for (int t = 0; t < 8; ++t) pk[t] = adj[i + t];
        float v[8];
        #pragma unroll
        for (int t = 0; t < 8; ++t)
            v[t] = bf2f(trans[(size_t)(pk[t] & 0xFFFFF) * 256 + (pk[t] >> 20) * 64 + lane]);
        a0 += v[0] + v[4]; a1 += v[1] + v[5]; a2 += v[2] + v[6]; a3 += v[3] + v[7];
    }
    for (; i + 2 <= end; i += 2) {
        int pk0 = adj[i], pk1 = adj[i + 1];
        a0 += bf2f(trans[(size_t)(pk0 & 0xFFFFF) * 256 + (pk0 >> 20) * 64 + lane]);
        a1 += bf2f(trans[(size_t)(pk1 & 0xFFFFF) * 256 + (pk1 >> 20) * 64 + lane]);
    }
    if (i < end) {
        int pk = adj[i];
        a2 += bf2f(trans[(size_t)(pk & 0xFFFFF) * 256 + (pk >> 20) * 64 + lane]);
    }
    alds[w * 72 + lane] = (a0 + a1) + (a2 + a3);
    __syncthreads();
    if (threadIdx.x < 256) {
        int bi = threadIdx.x >> 4, u = threadIdx.x & 15;
        int b8 = bi & 7;
        bool ishi = bi < 8;
        short8 ov;
        #pragma unroll
        for (int j = 0; j < 8; ++j) {
            float v = alds[u * 72 + b8 * 8 + j];
            ushort_t hh = f2bf(v);
            ov[j] = ishi ? (short)hh : (short)f2bf(v - bf2f(hh));
        }
        *(short8*)&AH[((size_t)grp * 32 + (ishi ? b8 : 16 + b8)) * 128 + u * 8] = ov;
    }
}

// ---------------- per-graph mean pooling ----------------
__global__ __launch_bounds__(256) void k_pool(const int* __restrict__ n2g,
        const ushort_t* __restrict__ AH, float* __restrict__ hg) {
    int gidx = blockIdx.x;
    int lo = 0, hi = N_NODES;
    while (lo < hi) { int mid = (lo + hi) >> 1; if (n2g[mid] < gidx) lo = mid + 1; else hi = mid; }
    int s = lo;
    hi = N_NODES;
    while (lo < hi) { int mid = (lo + hi) >> 1; if (n2g[mid] < gidx + 1) lo = mid + 1; else hi = mid; }
    int e = lo;
    int w = threadIdx.x >> 6, lane = threadIdx.x & 63;
    int bh = 8 + (lane >> 3), bl = 24 + (lane >> 3), el = lane & 7;
    float sum = 0.f;
    for (int n = s + w; n < e; n += 4) {
        size_t base = (size_t)(n >> 4) * 4096 + (size_t)(n & 15) * 8;
        sum += bf2f(AH[base + bh * 128 + el]) + bf2f(AH[base + bl * 128 + el]);
    }
    __shared__ float red[4][64];
    red[w][lane] = sum;
    __syncthreads();
    if (threadIdx.x < 64) {
        float tot = red[0][lane] + red[1][lane] + red[2][lane] + red[3][lane];
        float cnt = (float)(e - s);
        hg[gidx * 64 + lane] = tot / fmaxf(cnt, 1.f);
    }
}

// ---------------- classifier ----------------
__global__ __launch_bounds__(64) void k_cls(const float* __restrict__ hg,
        const float* __restrict__ W1, const float* __restrict__ b1,
        const float* __restrict__ W2, const float* __restrict__ b2,
        float* __restrict__ out) {
    int gidx = blockIdx.x;
    __shared__ float v[64];
    __shared__ float m[32];
    v[threadIdx.x] = hg[gidx * 64 + threadIdx.x];
    __syncthreads();
    if (threadIdx.x < 32) {
        float a = b1[threadIdx.x];
        #pragma unroll 8
        for (int k = 0; k < 64; ++k) a = fmaf(v[k], W1[threadIdx.x * 64 + k], a);
        m[threadIdx.x] = fmaxf(a, 0.f);
    }
    __syncthreads();
    if (threadIdx.x < 10) {
        float a = b2[threadIdx.x];
        #pragma unroll
        for (int j = 0; j < 32; ++j) a = fmaf(m[j], W2[threadIdx.x * 32 + j], a);
        out[gidx * 10 + threadIdx.x] = a;
    }
}

extern "C" void kernel_launch(void* const* d_in, const int* in_sizes, int n_in,
                              void* d_out, int out_size, void* d_ws, size_t ws_size,
                              hipStream_t stream) {
    const float* x    = (const float*)d_in[0];
    const int* src    = (const int*)d_in[1];
    const int* dst    = (const int*)d_in[2];
    const int* etype  = (const int*)d_in[3];
    const int* n2g    = (const int*)d_in[4];
    const float* W_in = (const float*)d_in[5];
    const float* b_in = (const float*)d_in[6];
    const float* We   = (const float*)d_in[7];
    const float* be   = (const float*)d_in[8];
    const float* W_ih = (const float*)d_in[9];
    const float* b_ih = (const float*)d_in[10];
    const float* W_hh = (const float*)d_in[11];
    const float* b_hh = (const float*)d_in[12];
    const float* W1   = (const float*)d_in[13];
    const float* b1   = (const float*)d_in[14];
    const float* W2   = (const float*)d_in[15];
    const float* b2   = (const float*)d_in[16];
    float* out = (float*)d_out;

    char* wsb = (char*)d_ws;
    size_t off = 0;
    auto alloc = [&](size_t bytes) -> void* {
        void* p = wsb + off;
        off += (bytes + 255) & ~(size_t)255;
        return p;
    };
    ushort_t* AH      = (ushort_t*)alloc((size_t)NGRP_PAD * 4096 * 2);   // 51.25 MB split [a|h]
    ushort_t* trans   = (ushort_t*)alloc((size_t)N_NODES * 256 * 2);     // 51.2 MB bf16
    int*      adj     = (int*)     alloc((size_t)N_EDGES * 4);
    int*      row_ptr = (int*)     alloc((size_t)(N_NODES + 1) * 4);
    int*      cursor  = (int*)     alloc((size_t)N_NODES * 4);
    int*      deg     = (int*)     alloc((size_t)N_NODES * 4);
    int*      bsum    = (int*)     alloc(1024);
    ushort_t* B1      = (ushort_t*)alloc((size_t)6 * 16 * 4 * 16 * 8 * 2);
    float*    bs1     = (float*)   alloc(256 * 4);
    ushort_t* B2      = (ushort_t*)alloc((size_t)12 * 16 * 4 * 16 * 8 * 2);
    float*    bg2     = (float*)   alloc(256 * 4);
    ushort_t* BIN     = (ushort_t*)alloc((size_t)24576 * 2);
    float*    hg      = (float*)   alloc(128 * 64 * 4);

    // zero padding groups so OOB-row reads are finite+deterministic
    hipMemsetAsync(AH + (size_t)NGRP * 4096, 0, (size_t)(NGRP_PAD - NGRP) * 4096 * 2, stream);

    hipLaunchKernelGGL(k_pack_b1, dim3(192), dim3(256), 0, stream, We, be, B1, bs1);
    hipLaunchKernelGGL(k_pack_b2, dim3(384), dim3(256), 0, stream, W_ih, b_ih, W_hh, b_hh, B2, bg2);
    hipLaunchKernelGGL(k_pack_bin, dim3(96), dim3(256), 0, stream, W_in, BIN);
    hipLaunchKernelGGL(k_linear_in, dim3((NGRP + 3) / 4), dim3(256), 0, stream, x, BIN, b_in, AH);

    hipMemsetAsync(deg, 0, (size_t)N_NODES * 4, stream);
    hipLaunchKernelGGL(k_hist, dim3((N_EDGES + 255) / 256), dim3(256), 0, stream, dst, deg);
    int nblk = (N_NODES + 1023) / 1024;
    hipLaunchKernelGGL(k_scan1, dim3(nblk), dim3(256), 0, stream, deg, row_ptr, bsum, N_NODES);
    hipLaunchKernelGGL(k_scan2, dim3(1), dim3(64), 0, stream, bsum, nblk, row_ptr + N_NODES);
    hipLaunchKernelGGL(k_scan3, dim3((N_NODES + 255) / 256), dim3(256), 0, stream, row_ptr, cursor, bsum, N_NODES);
    hipLaunchKernelGGL(k_fill, dim3((N_EDGES + 255) / 256), dim3(256), 0, stream, src, dst, etype, cursor, adj);

    int gblk = NGRP_PAD / 4;   // 1564
    for (int step = 0; step < STEPS; ++step) {
        hipLaunchKernelGGL(k_mm1, dim3(gblk), dim3(512), 0, stream, AH, B1, bs1, trans);
        hipLaunchKernelGGL(k_aggregate, dim3(NGRP), dim3(1024), 0, stream, row_ptr, adj, trans, AH);
        hipLaunchKernelGGL(k_mm2, dim3(gblk), dim3(512), 0, stream, AH, B2, bg2);
    }
    hipLaunchKernelGGL(k_pool, dim3(G_GRAPHS), dim3(256), 0, stream, n2g, AH, hg);
    hipLaunchKernelGGL(k_cls, dim3(G_GRAPHS), dim3(64), 0, stream, hg, W1, b1, W2, b2, out);
}

// Round 7
// 963.963 us; speedup vs baseline: 1.1206x; 1.1206x over previous
//
#include <hip/hip_runtime.h>
#include <hip/hip_bf16.h>
#include <math.h>

#define N_NODES 100000
#define N_EDGES 1000000
#define IN_DIM 128
#define HID 64
#define NET 4
#define STEPS 5
#define G_GRAPHS 128
#define LBL 10
#define NGRP 6250        // N_NODES / 16 (exact)
#define NGRP_PAD 6256    // padded to multiple of 8 (each mm block covers 8 groups)

typedef __attribute__((ext_vector_type(8))) short short8;
typedef __attribute__((ext_vector_type(4))) float f32x4;
typedef unsigned short ushort_t;

__device__ inline ushort_t f2bf(float v) {
    __hip_bfloat16 b = __float2bfloat16(v);
    return __builtin_bit_cast(ushort_t, b);
}
__device__ inline float bf2f(ushort_t u) {
    __hip_bfloat16 b = __builtin_bit_cast(__hip_bfloat16, u);
    return __bfloat162float(b);
}

// AH layout: [group][32 blocks][16 rows(u)][8 elems(j)] shorts.
// blocks 0-7: a-hi, 8-15: h-hi, 16-23: a-lo, 24-31: h-lo.  group stride = 4096 shorts.

// ---------------- pack B1: We -> [6 slices][16 ct][4 g][16 u][8 j] bf16 ----------------
// s0,s1: Whi (A h-hi k0-63) ; s2,s3: Whi (A h-lo) ; s4,s5: Wlo (A h-hi)
__global__ void k_pack_b1(const float* __restrict__ We, const float* __restrict__ be,
                          ushort_t* __restrict__ B1, float* __restrict__ bs1) {
    int idx = blockIdx.x * blockDim.x + threadIdx.x;
    if (idx >= 6 * 16 * 4 * 16 * 8) return;
    int j = idx & 7, u = (idx >> 3) & 15, g = (idx >> 7) & 3, ct = (idx >> 9) & 15, s = idx >> 13;
    int m = ct * 16 + u;
    int t = m >> 6, o = m & 63;
    int sk = (s < 2) ? s : (s < 4) ? (s - 2) : (s - 4);
    int k = sk * 32 + g * 8 + j;
    float val = We[t * 4096 + o * 64 + k];
    ushort_t hi = f2bf(val);
    B1[idx] = (s < 4) ? hi : f2bf(val - bf2f(hi));
    if (s == 0 && g == 0 && j == 0) bs1[m] = be[t * 64 + o];
}

// ---------------- pack B2: GRU fused weight -> [12][16][4][16][8] bf16 ----------------
// col m = q*64 + gate*16 + u ; slices 0-7: Whi (A-hi k0-127, A-lo k0-127) ; 8-11: Wlo (A-hi)
__global__ void k_pack_b2(const float* __restrict__ W_ih, const float* __restrict__ b_ih,
                          const float* __restrict__ W_hh, const float* __restrict__ b_hh,
                          ushort_t* __restrict__ B2, float* __restrict__ bg2) {
    int idx = blockIdx.x * blockDim.x + threadIdx.x;
    if (idx >= 12 * 16 * 4 * 16 * 8) return;
    int j = idx & 7, u = (idx >> 3) & 15, g = (idx >> 7) & 3, ct = (idx >> 9) & 15, s = idx >> 13;
    int m = ct * 16 + u;
    int q = m >> 6, gate = (m >> 4) & 3, c = q * 16 + (m & 15);
    int k = (s & 3) * 32 + g * 8 + j;
    float val;
    if (gate == 0)      { int jr = c;        val = (k < 64) ? W_ih[jr * 64 + k] : W_hh[jr * 64 + k - 64]; }
    else if (gate == 1) { int jr = 64 + c;   val = (k < 64) ? W_ih[jr * 64 + k] : W_hh[jr * 64 + k - 64]; }
    else if (gate == 2) { int jr = 128 + c;  val = (k < 64) ? W_ih[jr * 64 + k] : 0.f; }
    else                { int jr = 128 + c;  val = (k < 64) ? 0.f : W_hh[jr * 64 + k - 64]; }
    ushort_t hi = f2bf(val);
    B2[idx] = (s < 8) ? hi : f2bf(val - bf2f(hi));
    if (s == 0 && g == 0 && j == 0) {
        float bv;
        if (gate == 0)      bv = b_ih[c] + b_hh[c];
        else if (gate == 1) bv = b_ih[64 + c] + b_hh[64 + c];
        else if (gate == 2) bv = b_ih[128 + c];
        else                bv = b_hh[128 + c];
        bg2[m] = bv;
    }
}

// ---------------- pack BIN: W_in -> [12 slices][4 ct][64 lane][8 j] bf16 ----------------
__global__ void k_pack_bin(const float* __restrict__ W_in, ushort_t* __restrict__ BIN) {
    int idx = blockIdx.x * blockDim.x + threadIdx.x; // 12*4*64*8 = 24576
    if (idx >= 24576) return;
    int j = idx & 7, lu = (idx >> 3) & 63, ct = (idx >> 9) & 3, s = idx >> 11;
    int g = lu >> 4, u = lu & 15;
    int m = ct * 16 + u;
    int k = (s & 3) * 32 + g * 8 + j;
    float val = W_in[m * 128 + k];
    ushort_t hi = f2bf(val);
    BIN[idx] = (s < 8) ? hi : f2bf(val - bf2f(hi));
}

// ---------------- h0 = x @ W_in.T + b_in via MFMA ----------------
__global__ __launch_bounds__(256) void k_linear_in(const float* __restrict__ x,
        const ushort_t* __restrict__ BIN, const float* __restrict__ b_in,
        ushort_t* __restrict__ AH) {
    __shared__ float hlds[4][16 * 68];
    int tid = threadIdx.x;
    int lane = tid & 63, wp = tid >> 6;
    int g = lane >> 4, u = lane & 15;
    int grp = blockIdx.x * 4 + wp;
    bool ok = grp < NGRP;
    int row = ok ? (grp * 16 + u) : 0;
    short8 xhi[4], xlo[4];
    #pragma unroll
    for (int ks = 0; ks < 4; ++ks) {
        const float* xp = &x[(size_t)row * 128 + ks * 32 + g * 8];
        float4 v0 = ok ? *(const float4*)xp : make_float4(0.f, 0.f, 0.f, 0.f);
        float4 v1 = ok ? *(const float4*)(xp + 4) : make_float4(0.f, 0.f, 0.f, 0.f);
        float vv[8] = {v0.x, v0.y, v0.z, v0.w, v1.x, v1.y, v1.z, v1.w};
        #pragma unroll
        for (int j = 0; j < 8; ++j) {
            ushort_t hh = f2bf(vv[j]);
            xhi[ks][j] = (short)hh;
            xlo[ks][j] = (short)f2bf(vv[j] - bf2f(hh));
        }
    }
    f32x4 zero = {0.f, 0.f, 0.f, 0.f};
    f32x4 acc[4] = {zero, zero, zero, zero};
    #pragma unroll
    for (int s = 0; s < 12; ++s) {
        int ks = s & 3;
        short8 af = (s < 4) ? xhi[ks] : (s < 8) ? xlo[ks] : xhi[ks];
        #pragma unroll
        for (int ct = 0; ct < 4; ++ct) {
            short8 bf = *(const short8*)&BIN[((size_t)(s * 4 + ct) * 64 + lane) * 8];
            acc[ct] = __builtin_amdgcn_mfma_f32_16x16x32_bf16(af, bf, acc[ct], 0, 0, 0);
        }
    }
    #pragma unroll
    for (int ct = 0; ct < 4; ++ct) {
        float bo = b_in[ct * 16 + u];
        #pragma unroll
        for (int j = 0; j < 4; ++j)
            hlds[wp][(g * 4 + j) * 68 + ct * 16 + u] = acc[ct][j] + bo;
    }
    __syncthreads();
    #pragma unroll
    for (int k = 0; k < 4; ++k) {
        int bi = g + 4 * k;      // 0..15
        short8 ov;
        #pragma unroll
        for (int j = 0; j < 8; ++j) {
            float v = hlds[wp][u * 68 + (bi & 7) * 8 + j];
            ushort_t hh = f2bf(v);
            ov[j] = (bi < 8) ? (short)hh : (short)f2bf(v - bf2f(hh));
        }
        int blk = (bi < 8) ? (8 + bi) : (24 + (bi - 8));
        if (ok) *(short8*)&AH[((size_t)grp * 32 + blk) * 128 + u * 8] = ov;
    }
}

// ---------------- CSR build (once per call) ----------------
__global__ void k_hist(const int* __restrict__ dst, int* __restrict__ deg) {
    int e = blockIdx.x * blockDim.x + threadIdx.x;
    if (e < N_EDGES) atomicAdd(&deg[dst[e]], 1);
}

__global__ __launch_bounds__(256) void k_scan1(const int* __restrict__ deg,
        int* __restrict__ ex, int* __restrict__ bsum, int n) {
    __shared__ int ts[256];
    int base = blockIdx.x * 1024;
    int vals[4]; int s = 0;
    #pragma unroll
    for (int i = 0; i < 4; ++i) {
        int idx = base + threadIdx.x * 4 + i;
        vals[i] = (idx < n) ? deg[idx] : 0;
        s += vals[i];
    }
    ts[threadIdx.x] = s;
    __syncthreads();
    for (int off = 1; off < 256; off <<= 1) {
        int v = (threadIdx.x >= off) ? ts[threadIdx.x - off] : 0;
        __syncthreads();
        ts[threadIdx.x] += v;
        __syncthreads();
    }
    int run = (threadIdx.x == 0) ? 0 : ts[threadIdx.x - 1];
    #pragma unroll
    for (int i = 0; i < 4; ++i) {
        int idx = base + threadIdx.x * 4 + i;
        if (idx < n) ex[idx] = run;
        run += vals[i];
    }
    if (threadIdx.x == 255) bsum[blockIdx.x] = ts[255];
}

__global__ void k_scan2(int* bsum, int nb, int* row_ptr_end) {
    if (threadIdx.x == 0 && blockIdx.x == 0) {
        int run = 0;
        for (int i = 0; i < nb; ++i) { int t = bsum[i]; bsum[i] = run; run += t; }
        *row_ptr_end = run;
    }
}

__global__ void k_scan3(int* __restrict__ row_ptr, int* __restrict__ cursor,
                        const int* __restrict__ bsum, int n) {
    int i = blockIdx.x * blockDim.x + threadIdx.x;
    if (i < n) {
        int v = row_ptr[i] + bsum[i >> 10];
        row_ptr[i] = v;
        cursor[i] = v;
    }
}

__global__ void k_fill(const int* __restrict__ src, const int* __restrict__ dst,
                       const int* __restrict__ et, int* __restrict__ cursor,
                       int* __restrict__ adj) {
    int e = blockIdx.x * blockDim.x + threadIdx.x;
    if (e < N_EDGES) {
        int d = dst[e];
        int p = atomicAdd(&cursor[d], 1);
        adj[p] = src[e] | (et[e] << 20);
    }
}

// ---------------- GEMM1: trans[N,256](bf16) = split3(h) x B1 ----------------
// 128 rows/block (8 groups), 8 waves = (rp 0..1) x (q 0..3); A h-blocks staged in LDS.
__global__ __launch_bounds__(512) void k_mm1(const ushort_t* __restrict__ AH,
        const ushort_t* __restrict__ B1, const float* __restrict__ bs1,
        ushort_t* __restrict__ trans) {
    __shared__ ushort_t lds[16896];   // union: A-stage 16384 shorts / epi 64*264
    int tid = threadIdx.x;
    size_t gb = (size_t)blockIdx.x * 8;
    // stage h-hi/h-lo of 8 groups: layout [gl][part][8 blocks][16 u][8 j] = 16384 shorts
    #pragma unroll
    for (int it = 0; it < 4; ++it) {
        int f = it * 512 + tid;            // 0..2047 chunks of 16B
        int gl = f >> 8, part = (f >> 7) & 1, inner = f & 127;
        size_t srcp = ((gb + gl) * 32 + (part ? 24 : 8)) * 128 + (size_t)inner * 8;
        *(short8*)&lds[f * 8] = *(const short8*)&AH[srcp];
    }
    __syncthreads();
    int lane = tid & 63, wp = tid >> 6;
    int q = wp & 3, rp = wp >> 2;
    int g = lane >> 4, u = lane & 15;
    int n0 = blockIdx.x * 128;
    f32x4 zero = {0.f, 0.f, 0.f, 0.f};
    f32x4 acc[4][4];
    #pragma unroll
    for (int i = 0; i < 4; ++i)
        #pragma unroll
        for (int j = 0; j < 4; ++j) acc[i][j] = zero;
    #pragma unroll
    for (int s = 0; s < 6; ++s) {
        // local A index: part = 1 for slices 2,3 (h-lo); lb = (s odd ? 4 : 0) + g
        int part = (s == 2 || s == 3) ? 1 : 0;
        int lb = ((s & 1) ? 4 : 0) + g;
        short8 bfr[4], afr[4];
        #pragma unroll
        for (int ct = 0; ct < 4; ++ct)
            bfr[ct] = *(const short8*)&B1[((size_t)(s * 16 + q * 4 + ct) * 64 + g * 16 + u) * 8];
        #pragma unroll
        for (int rt = 0; rt < 4; ++rt) {
            int gl = rp * 4 + rt;
            afr[rt] = *(const short8*)&lds[((gl * 2 + part) * 8 + lb) * 128 + u * 8];
        }
        #pragma unroll
        for (int rt = 0; rt < 4; ++rt)
            #pragma unroll
            for (int ct = 0; ct < 4; ++ct)
                acc[rt][ct] = __builtin_amdgcn_mfma_f32_16x16x32_bf16(afr[rt], bfr[ct], acc[rt][ct], 0, 0, 0);
    }
    float bsv[4];
    #pragma unroll
    for (int ct = 0; ct < 4; ++ct) bsv[ct] = bs1[q * 64 + ct * 16 + u];
    #pragma unroll
    for (int h = 0; h < 2; ++h) {
        __syncthreads();
        if (rp == h) {
            #pragma unroll
            for (int rt = 0; rt < 4; ++rt)
                #pragma unroll
                for (int ct = 0; ct < 4; ++ct)
                    #pragma unroll
                    for (int j = 0; j < 4; ++j) {
                        int rl = rt * 16 + g * 4 + j;
                        lds[rl * 264 + q * 64 + ct * 16 + u] = f2bf(acc[rt][ct][j] + bsv[ct]);
                    }
        }
        __syncthreads();
        int rl = tid >> 3, seg = tid & 7;
        int n = n0 + h * 64 + rl;
        if (n < N_NODES) {
            #pragma unroll
            for (int i = 0; i < 4; ++i) {
                short8 v = *(const short8*)&lds[rl * 264 + seg * 32 + i * 8];
                *(short8*)&trans[(size_t)n * 256 + seg * 32 + i * 8] = v;
            }
        }
    }
}

// ---------------- GEMM2 + GRU: h = GRU(a,h), A staged in LDS, h updated in-place ----------------
__global__ __launch_bounds__(512) void k_mm2(ushort_t* __restrict__ AH,
        const ushort_t* __restrict__ B2, const float* __restrict__ bg2) {
    __shared__ ushort_t lds[32768];   // 64KB: 8 groups x 4096 shorts, exact AH image
    int tid = threadIdx.x;
    size_t base = (size_t)blockIdx.x * 8 * 4096;
    #pragma unroll
    for (int it = 0; it < 8; ++it) {
        int f = it * 512 + tid;            // 0..4095 chunks of 16B
        *(short8*)&lds[f * 8] = *(const short8*)&AH[base + (size_t)f * 8];
    }
    __syncthreads();
    int lane = tid & 63, wp = tid >> 6;
    int q = wp & 3, rp = wp >> 2;
    int g = lane >> 4, u = lane & 15;
    f32x4 zero = {0.f, 0.f, 0.f, 0.f};
    f32x4 acc[4][4];
    #pragma unroll
    for (int i = 0; i < 4; ++i)
        #pragma unroll
        for (int j = 0; j < 4; ++j) acc[i][j] = zero;
    const int bb2[12] = {0, 4, 8, 12, 16, 20, 24, 28, 0, 4, 8, 12};
    #pragma unroll
    for (int s = 0; s < 12; ++s) {
        short8 bfr[4], afr[4];
        #pragma unroll
        for (int ct = 0; ct < 4; ++ct)
            bfr[ct] = *(const short8*)&B2[((size_t)(s * 16 + q * 4 + ct) * 64 + g * 16 + u) * 8];
        #pragma unroll
        for (int rt = 0; rt < 4; ++rt) {
            int gl = rp * 4 + rt;
            afr[rt] = *(const short8*)&lds[(gl * 32 + bb2[s] + g) * 128 + u * 8];
        }
        #pragma unroll
        for (int rt = 0; rt < 4; ++rt)
            #pragma unroll
            for (int ct = 0; ct < 4; ++ct)
                acc[rt][ct] = __builtin_amdgcn_mfma_f32_16x16x32_bf16(afr[rt], bfr[ct], acc[rt][ct], 0, 0, 0);
    }
    __syncthreads();   // all LDS A-reads done before h-blocks are overwritten
    float bgv[4];
    #pragma unroll
    for (int ct = 0; ct < 4; ++ct) bgv[ct] = bg2[q * 64 + ct * 16 + u];
    int hid = q * 16 + u;
    int bhi = 8 + (hid >> 3), blo = 24 + (hid >> 3), el = hid & 7;
    #pragma unroll
    for (int rt = 0; rt < 4; ++rt) {
        int gl = rp * 4 + rt;
        #pragma unroll
        for (int j = 0; j < 4; ++j) {
            int uu = g * 4 + j;
            int shi = (gl * 32 + bhi) * 128 + uu * 8 + el;
            int slo = (gl * 32 + blo) * 128 + uu * 8 + el;
            float ho = bf2f(lds[shi]) + bf2f(lds[slo]);
            float rs  = acc[rt][0][j] + bgv[0];
            float zs  = acc[rt][1][j] + bgv[1];
            float inn = acc[rt][2][j] + bgv[2];
            float hnn = acc[rt][3][j] + bgv[3];
            float r = 1.f / (1.f + __expf(-rs));
            float z = 1.f / (1.f + __expf(-zs));
            float t = inn + r * hnn;
            float e2 = __expf(2.f * t);
            float nn = 1.f - 2.f / (e2 + 1.f);   // tanh(t), NaN-free
            float hnew = (1.f - z) * nn + z * ho;
            ushort_t hh = f2bf(hnew);
            lds[shi] = hh;
            lds[slo] = f2bf(hnew - bf2f(hh));
        }
    }
    __syncthreads();
    // pack-out: h-hi (8..15) and h-lo (24..31) blocks of 8 groups -> global, coalesced
    #pragma unroll
    for (int it = 0; it < 4; ++it) {
        int c = it * 512 + tid;            // 0..2047
        int gl = c >> 8, r = c & 255, bi = r >> 4, uu = r & 15;
        int blk = (bi < 8) ? (8 + bi) : (16 + bi);   // 8..15, 24..31
        int lofs = (gl * 32 + blk) * 128 + uu * 8;
        short8 v = *(const short8*)&lds[lofs];
        *(short8*)&AH[base + (size_t)lofs] = v;
    }
}

// ---------------- aggregation via CSR; 1 node per wave, unroll-8 MLP ----------------
__global__ __launch_bounds__(1024) void k_aggregate(const int* __restrict__ row_ptr,
        const int* __restrict__ adj, const ushort_t* __restrict__ trans,
        ushort_t* __restrict__ AH) {
    __shared__ float alds[16 * 72];
    int w = threadIdx.x >> 6, lane = threadIdx.x & 63;
    int grp = blockIdx.x;
    int n = grp * 16 + w;
    int beg = row_ptr[n], end = row_ptr[n + 1];
    float a0 = 0.f, a1 = 0.f, a2 = 0.f, a3 = 0.f;
    int i = beg;
    for (; i + 8 <= end; i += 8) {
        int pk[8];
        #pragma unroll
        for (int t = 0; t < 8; ++t) pk[t] = adj[i + t];
        float v[8];
        #pragma unroll
        for (int t = 0; t < 8; ++t)
            v[t] = bf2f(trans[(size_t)(pk[t] & 0xFFFFF) * 256 + (pk[t] >> 20) * 64 + lane]);
        a0 += v[0] + v[4]; a1 += v[1] + v[5]; a2 += v[2] + v[6]; a3 += v[3] + v[7];
    }
    for (; i + 2 <= end; i += 2) {
        int pk0 = adj[i], pk1 = adj[i + 1];
        a0 += bf2f(trans[(size_t)(pk0 & 0xFFFFF) * 256 + (pk0 >> 20) * 64 + lane]);
        a1 += bf2f(trans[(size_t)(pk1 & 0xFFFFF) * 256 + (pk1 >> 20) * 64 + lane]);
    }
    if (i < end) {
        int pk = adj[i];
        a2 += bf2f(trans[(size_t)(pk & 0xFFFFF) * 256 + (pk >> 20) * 64 + lane]);
    }
    alds[w * 72 + lane] = (a0 + a1) + (a2 + a3);
    __syncthreads();
    if (threadIdx.x < 256) {
        int bi = threadIdx.x >> 4, u = threadIdx.x & 15;
        int b8 = bi & 7;
        bool ishi = bi < 8;
        short8 ov;
        #pragma unroll
        for (int j = 0; j < 8; ++j) {
            float v = alds[u * 72 + b8 * 8 + j];
            ushort_t hh = f2bf(v);
            ov[j] = ishi ? (short)hh : (short)f2bf(v - bf2f(hh));
        }
        *(short8*)&AH[((size_t)grp * 32 + (ishi ? b8 : 16 + b8)) * 128 + u * 8] = ov;
    }
}

// ---------------- per-graph mean pooling ----------------
__global__ __launch_bounds__(256) void k_pool(const int* __restrict__ n2g,
        const ushort_t* __restrict__ AH, float* __restrict__ hg) {
    int gidx = blockIdx.x;
    int lo = 0, hi = N_NODES;
    while (lo < hi) { int mid = (lo + hi) >> 1; if (n2g[mid] < gidx) lo = mid + 1; else hi = mid; }
    int s = lo;
    hi = N_NODES;
    while (lo < hi) { int mid = (lo + hi) >> 1; if (n2g[mid] < gidx + 1) lo = mid + 1; else hi = mid; }
    int e = lo;
    int w = threadIdx.x >> 6, lane = threadIdx.x & 63;
    int bh = 8 + (lane >> 3), bl = 24 + (lane >> 3), el = lane & 7;
    float sum = 0.f;
    for (int n = s + w; n < e; n += 4) {
        size_t base = (size_t)(n >> 4) * 4096 + (size_t)(n & 15) * 8;
        sum += bf2f(AH[base + bh * 128 + el]) + bf2f(AH[base + bl * 128 + el]);
    }
    __shared__ float red[4][64];
    red[w][lane] = sum;
    __syncthreads();
    if (threadIdx.x < 64) {
        float tot = red[0][lane] + red[1][lane] + red[2][lane] + red[3][lane];
        float cnt = (float)(e - s);
        hg[gidx * 64 + lane] = tot / fmaxf(cnt, 1.f);
    }
}

// ---------------- classifier ----------------
__global__ __launch_bounds__(64) void k_cls(const float* __restrict__ hg,
        const float* __restrict__ W1, const float* __restrict__ b1,
        const float* __restrict__ W2, const float* __restrict__ b2,
        float* __restrict__ out) {
    int gidx = blockIdx.x;
    __shared__ float v[64];
    __shared__ float m[32];
    v[threadIdx.x] = hg[gidx * 64 + threadIdx.x];
    __syncthreads();
    if (threadIdx.x < 32) {
        float a = b1[threadIdx.x];
        #pragma unroll 8
        for (int k = 0; k < 64; ++k) a = fmaf(v[k], W1[threadIdx.x * 64 + k], a);
        m[threadIdx.x] = fmaxf(a, 0.f);
    }
    __syncthreads();
    if (threadIdx.x < 10) {
        float a = b2[threadIdx.x];
        #pragma unroll
        for (int j = 0; j < 32; ++j) a = fmaf(m[j], W2[threadIdx.x * 32 + j], a);
        out[gidx * 10 + threadIdx.x] = a;
    }
}

extern "C" void kernel_launch(void* const* d_in, const int* in_sizes, int n_in,
                              void* d_out, int out_size, void* d_ws, size_t ws_size,
                              hipStream_t stream) {
    const float* x    = (const float*)d_in[0];
    const int* src    = (const int*)d_in[1];
    const int* dst    = (const int*)d_in[2];
    const int* etype  = (const int*)d_in[3];
    const int* n2g    = (const int*)d_in[4];
    const float* W_in = (const float*)d_in[5];
    const float* b_in = (const float*)d_in[6];
    const float* We   = (const float*)d_in[7];
    const float* be   = (const float*)d_in[8];
    const float* W_ih = (const float*)d_in[9];
    const float* b_ih = (const float*)d_in[10];
    const float* W_hh = (const float*)d_in[11];
    const float* b_hh = (const float*)d_in[12];
    const float* W1   = (const float*)d_in[13];
    const float* b1   = (const float*)d_in[14];
    const float* W2   = (const float*)d_in[15];
    const float* b2   = (const float*)d_in[16];
    float* out = (float*)d_out;

    char* wsb = (char*)d_ws;
    size_t off = 0;
    auto alloc = [&](size_t bytes) -> void* {
        void* p = wsb + off;
        off += (bytes + 255) & ~(size_t)255;
        return p;
    };
    ushort_t* AH      = (ushort_t*)alloc((size_t)NGRP_PAD * 4096 * 2);   // 51.25 MB split [a|h]
    ushort_t* trans   = (ushort_t*)alloc((size_t)N_NODES * 256 * 2);     // 51.2 MB bf16
    int*      adj     = (int*)     alloc((size_t)N_EDGES * 4);
    int*      row_ptr = (int*)     alloc((size_t)(N_NODES + 1) * 4);
    int*      cursor  = (int*)     alloc((size_t)N_NODES * 4);
    int*      deg     = (int*)     alloc((size_t)N_NODES * 4);
    int*      bsum    = (int*)     alloc(1024);
    ushort_t* B1      = (ushort_t*)alloc((size_t)6 * 16 * 4 * 16 * 8 * 2);
    float*    bs1     = (float*)   alloc(256 * 4);
    ushort_t* B2      = (ushort_t*)alloc((size_t)12 * 16 * 4 * 16 * 8 * 2);
    float*    bg2     = (float*)   alloc(256 * 4);
    ushort_t* BIN     = (ushort_t*)alloc((size_t)24576 * 2);
    float*    hg      = (float*)   alloc(128 * 64 * 4);

    // zero padding groups so OOB-row reads are finite+deterministic
    hipMemsetAsync(AH + (size_t)NGRP * 4096, 0, (size_t)(NGRP_PAD - NGRP) * 4096 * 2, stream);

    hipLaunchKernelGGL(k_pack_b1, dim3(192), dim3(256), 0, stream, We, be, B1, bs1);
    hipLaunchKernelGGL(k_pack_b2, dim3(384), dim3(256), 0, stream, W_ih, b_ih, W_hh, b_hh, B2, bg2);
    hipLaunchKernelGGL(k_pack_bin, dim3(96), dim3(256), 0, stream, W_in, BIN);
    hipLaunchKernelGGL(k_linear_in, dim3((NGRP + 3) / 4), dim3(256), 0, stream, x, BIN, b_in, AH);

    hipMemsetAsync(deg, 0, (size_t)N_NODES * 4, stream);
    hipLaunchKernelGGL(k_hist, dim3((N_EDGES + 255) / 256), dim3(256), 0, stream, dst, deg);
    int nblk = (N_NODES + 1023) / 1024;
    hipLaunchKernelGGL(k_scan1, dim3(nblk), dim3(256), 0, stream, deg, row_ptr, bsum, N_NODES);
    hipLaunchKernelGGL(k_scan2, dim3(1), dim3(64), 0, stream, bsum, nblk, row_ptr + N_NODES);
    hipLaunchKernelGGL(k_scan3, dim3((N_NODES + 255) / 256), dim3(256), 0, stream, row_ptr, cursor, bsum, N_NODES);
    hipLaunchKernelGGL(k_fill, dim3((N_EDGES + 255) / 256), dim3(256), 0, stream, src, dst, etype, cursor, adj);

    int gblk = NGRP_PAD / 8;   // 782
    for (int step = 0; step < STEPS; ++step) {
        hipLaunchKernelGGL(k_mm1, dim3(gblk), dim3(512), 0, stream, AH, B1, bs1, trans);
        hipLaunchKernelGGL(k_aggregate, dim3(NGRP), dim3(1024), 0, stream, row_ptr, adj, trans, AH);
        hipLaunchKernelGGL(k_mm2, dim3(gblk), dim3(512), 0, stream, AH, B2, bg2);
    }
    hipLaunchKernelGGL(k_pool, dim3(G_GRAPHS), dim3(256), 0, stream, n2g, AH, hg);
    hipLaunchKernelGGL(k_cls, dim3(G_GRAPHS), dim3(64), 0, stream, hg, W1, b1, W2, b2, out);
}

// Round 8
// 877.048 us; speedup vs baseline: 1.2316x; 1.0991x over previous
//
#include <hip/hip_runtime.h>
#include <hip/hip_bf16.h>
#include <math.h>

#define N_NODES 100000
#define N_EDGES 1000000
#define IN_DIM 128
#define HID 64
#define NET 4
#define STEPS 5
#define G_GRAPHS 128
#define LBL 10
#define NGRP 6250        // N_NODES / 16 (exact)
#define NGRP_PAD 6256    // padded to multiple of 8 (each mm block covers 8 groups)
#define NBKT 1024        // CSR buckets of 128 nodes
#define TILE_E 8192      // edges per bscatter block

typedef __attribute__((ext_vector_type(8))) short short8;
typedef __attribute__((ext_vector_type(4))) float f32x4;
typedef unsigned short ushort_t;

__device__ inline ushort_t f2bf(float v) {
    __hip_bfloat16 b = __float2bfloat16(v);
    return __builtin_bit_cast(ushort_t, b);
}
__device__ inline float bf2f(ushort_t u) {
    __hip_bfloat16 b = __builtin_bit_cast(__hip_bfloat16, u);
    return __bfloat162float(b);
}

// AH layout: [group][32 blocks][16 rows(u)][8 elems(j)] shorts.
// blocks 0-7: a-hi, 8-15: h-hi, 16-23: a-lo, 24-31: h-lo.  group stride = 4096 shorts.

// ---------------- pack B1: We -> [6 slices][16 ct][4 g][16 u][8 j] bf16 ----------------
__global__ void k_pack_b1(const float* __restrict__ We, const float* __restrict__ be,
                          ushort_t* __restrict__ B1, float* __restrict__ bs1) {
    int idx = blockIdx.x * blockDim.x + threadIdx.x;
    if (idx >= 6 * 16 * 4 * 16 * 8) return;
    int j = idx & 7, u = (idx >> 3) & 15, g = (idx >> 7) & 3, ct = (idx >> 9) & 15, s = idx >> 13;
    int m = ct * 16 + u;
    int t = m >> 6, o = m & 63;
    int sk = (s < 2) ? s : (s < 4) ? (s - 2) : (s - 4);
    int k = sk * 32 + g * 8 + j;
    float val = We[t * 4096 + o * 64 + k];
    ushort_t hi = f2bf(val);
    B1[idx] = (s < 4) ? hi : f2bf(val - bf2f(hi));
    if (s == 0 && g == 0 && j == 0) bs1[m] = be[t * 64 + o];
}

// ---------------- pack B2: GRU fused weight -> [12][16][4][16][8] bf16 ----------------
__global__ void k_pack_b2(const float* __restrict__ W_ih, const float* __restrict__ b_ih,
                          const float* __restrict__ W_hh, const float* __restrict__ b_hh,
                          ushort_t* __restrict__ B2, float* __restrict__ bg2) {
    int idx = blockIdx.x * blockDim.x + threadIdx.x;
    if (idx >= 12 * 16 * 4 * 16 * 8) return;
    int j = idx & 7, u = (idx >> 3) & 15, g = (idx >> 7) & 3, ct = (idx >> 9) & 15, s = idx >> 13;
    int m = ct * 16 + u;
    int q = m >> 6, gate = (m >> 4) & 3, c = q * 16 + (m & 15);
    int k = (s & 3) * 32 + g * 8 + j;
    float val;
    if (gate == 0)      { int jr = c;        val = (k < 64) ? W_ih[jr * 64 + k] : W_hh[jr * 64 + k - 64]; }
    else if (gate == 1) { int jr = 64 + c;   val = (k < 64) ? W_ih[jr * 64 + k] : W_hh[jr * 64 + k - 64]; }
    else if (gate == 2) { int jr = 128 + c;  val = (k < 64) ? W_ih[jr * 64 + k] : 0.f; }
    else                { int jr = 128 + c;  val = (k < 64) ? 0.f : W_hh[jr * 64 + k - 64]; }
    ushort_t hi = f2bf(val);
    B2[idx] = (s < 8) ? hi : f2bf(val - bf2f(hi));
    if (s == 0 && g == 0 && j == 0) {
        float bv;
        if (gate == 0)      bv = b_ih[c] + b_hh[c];
        else if (gate == 1) bv = b_ih[64 + c] + b_hh[64 + c];
        else if (gate == 2) bv = b_ih[128 + c];
        else                bv = b_hh[128 + c];
        bg2[m] = bv;
    }
}

// ---------------- pack BIN: W_in -> [12 slices][4 ct][64 lane][8 j] bf16 ----------------
__global__ void k_pack_bin(const float* __restrict__ W_in, ushort_t* __restrict__ BIN) {
    int idx = blockIdx.x * blockDim.x + threadIdx.x; // 12*4*64*8 = 24576
    if (idx >= 24576) return;
    int j = idx & 7, lu = (idx >> 3) & 63, ct = (idx >> 9) & 3, s = idx >> 11;
    int g = lu >> 4, u = lu & 15;
    int m = ct * 16 + u;
    int k = (s & 3) * 32 + g * 8 + j;
    float val = W_in[m * 128 + k];
    ushort_t hi = f2bf(val);
    BIN[idx] = (s < 8) ? hi : f2bf(val - bf2f(hi));
}

// ---------------- h0 = x @ W_in.T + b_in via MFMA ----------------
__global__ __launch_bounds__(256) void k_linear_in(const float* __restrict__ x,
        const ushort_t* __restrict__ BIN, const float* __restrict__ b_in,
        ushort_t* __restrict__ AH) {
    __shared__ float hlds[4][16 * 68];
    int tid = threadIdx.x;
    int lane = tid & 63, wp = tid >> 6;
    int g = lane >> 4, u = lane & 15;
    int grp = blockIdx.x * 4 + wp;
    bool ok = grp < NGRP;
    int row = ok ? (grp * 16 + u) : 0;
    short8 xhi[4], xlo[4];
    #pragma unroll
    for (int ks = 0; ks < 4; ++ks) {
        const float* xp = &x[(size_t)row * 128 + ks * 32 + g * 8];
        float4 v0 = ok ? *(const float4*)xp : make_float4(0.f, 0.f, 0.f, 0.f);
        float4 v1 = ok ? *(const float4*)(xp + 4) : make_float4(0.f, 0.f, 0.f, 0.f);
        float vv[8] = {v0.x, v0.y, v0.z, v0.w, v1.x, v1.y, v1.z, v1.w};
        #pragma unroll
        for (int j = 0; j < 8; ++j) {
            ushort_t hh = f2bf(vv[j]);
            xhi[ks][j] = (short)hh;
            xlo[ks][j] = (short)f2bf(vv[j] - bf2f(hh));
        }
    }
    f32x4 zero = {0.f, 0.f, 0.f, 0.f};
    f32x4 acc[4] = {zero, zero, zero, zero};
    #pragma unroll
    for (int s = 0; s < 12; ++s) {
        int ks = s & 3;
        short8 af = (s < 4) ? xhi[ks] : (s < 8) ? xlo[ks] : xhi[ks];
        #pragma unroll
        for (int ct = 0; ct < 4; ++ct) {
            short8 bf = *(const short8*)&BIN[((size_t)(s * 4 + ct) * 64 + lane) * 8];
            acc[ct] = __builtin_amdgcn_mfma_f32_16x16x32_bf16(af, bf, acc[ct], 0, 0, 0);
        }
    }
    #pragma unroll
    for (int ct = 0; ct < 4; ++ct) {
        float bo = b_in[ct * 16 + u];
        #pragma unroll
        for (int j = 0; j < 4; ++j)
            hlds[wp][(g * 4 + j) * 68 + ct * 16 + u] = acc[ct][j] + bo;
    }
    __syncthreads();
    #pragma unroll
    for (int k = 0; k < 4; ++k) {
        int bi = g + 4 * k;      // 0..15
        short8 ov;
        #pragma unroll
        for (int j = 0; j < 8; ++j) {
            float v = hlds[wp][u * 68 + (bi & 7) * 8 + j];
            ushort_t hh = f2bf(v);
            ov[j] = (bi < 8) ? (short)hh : (short)f2bf(v - bf2f(hh));
        }
        int blk = (bi < 8) ? (8 + bi) : (24 + (bi - 8));
        if (ok) *(short8*)&AH[((size_t)grp * 32 + blk) * 128 + u * 8] = ov;
    }
}

// ================= CSR build: two-level bucket sort =================
// bucket b = dst >> 7 (128 nodes per bucket, 1024 buckets)

__global__ __launch_bounds__(256) void k_bhist(const int* __restrict__ dst,
        int* __restrict__ bhist) {
    __shared__ int h[NBKT];
    for (int i = threadIdx.x; i < NBKT; i += 256) h[i] = 0;
    __syncthreads();
    int idx = blockIdx.x * 256 + threadIdx.x;
    for (int e = idx; e < N_EDGES; e += 256 * 256) atomicAdd(&h[dst[e] >> 7], 1);
    __syncthreads();
    for (int i = threadIdx.x; i < NBKT; i += 256) {
        int c = h[i];
        if (c) atomicAdd(&bhist[i], c);
    }
}

__global__ __launch_bounds__(1024) void k_bscan(const int* __restrict__ bhist,
        int* __restrict__ bbase, int* __restrict__ bcursor) {
    __shared__ int ts[NBKT];
    int t = threadIdx.x;
    int v = bhist[t];
    ts[t] = v;
    __syncthreads();
    for (int off = 1; off < NBKT; off <<= 1) {
        int u = (t >= off) ? ts[t - off] : 0;
        __syncthreads();
        ts[t] += u;
        __syncthreads();
    }
    int excl = ts[t] - v;
    bbase[t] = excl;
    bcursor[t] = excl;
    if (t == NBKT - 1) bbase[NBKT] = ts[NBKT - 1];
}

// payload: src(0..16) | et<<20 | (dst&127)<<22
__global__ __launch_bounds__(512) void k_bscatter(const int* __restrict__ src,
        const int* __restrict__ dst, const int* __restrict__ et,
        int* __restrict__ bcursor, unsigned int* __restrict__ ebuf) {
    __shared__ int hcnt[NBKT], loff[NBKT], gpos[NBKT], ps[512];
    __shared__ unsigned int stage[TILE_E];
    __shared__ unsigned short sbkt[TILE_E];
    int tid = threadIdx.x;
    int base = blockIdx.x * TILE_E;
    int tilecnt = min(TILE_E, N_EDGES - base);
    for (int i = tid; i < NBKT; i += 512) hcnt[i] = 0;
    __syncthreads();
    #pragma unroll
    for (int k = 0; k < TILE_E / 512; ++k) {
        int e = base + tid + k * 512;
        if (e < N_EDGES) atomicAdd(&hcnt[dst[e] >> 7], 1);
    }
    __syncthreads();
    int c0 = hcnt[tid * 2], c1 = hcnt[tid * 2 + 1];
    ps[tid] = c0 + c1;
    __syncthreads();
    for (int off = 1; off < 512; off <<= 1) {
        int u = (tid >= off) ? ps[tid - off] : 0;
        __syncthreads();
        ps[tid] += u;
        __syncthreads();
    }
    int ex = ps[tid] - (c0 + c1);
    loff[tid * 2] = ex;
    loff[tid * 2 + 1] = ex + c0;
    for (int b = tid; b < NBKT; b += 512) {
        int c = hcnt[b];
        gpos[b] = c ? atomicAdd(&bcursor[b], c) : 0;
    }
    __syncthreads();
    for (int i = tid; i < NBKT; i += 512) hcnt[i] = 0;
    __syncthreads();
    #pragma unroll
    for (int k = 0; k < TILE_E / 512; ++k) {
        int e = base + tid + k * 512;
        if (e < N_EDGES) {
            int d = dst[e];
            int b = d >> 7;
            int r = atomicAdd(&hcnt[b], 1);
            int lp = loff[b] + r;
            stage[lp] = (unsigned int)src[e] | ((unsigned int)et[e] << 20)
                      | ((unsigned int)(d & 127) << 22);
            sbkt[lp] = (unsigned short)b;
        }
    }
    __syncthreads();
    for (int i = tid; i < tilecnt; i += 512) {
        int b = sbkt[i];
        ebuf[gpos[b] + (i - loff[b])] = stage[i];
    }
}

// per-bucket: node-level CSR within the bucket's contiguous edge range; writes row_ptr too
__global__ __launch_bounds__(256) void k_bcsr(const unsigned int* __restrict__ ebuf,
        const int* __restrict__ bbase, int* __restrict__ adj, int* __restrict__ row_ptr) {
    __shared__ int ncnt[128], noff[129], nps[128];
    int b = blockIdx.x;
    int tid = threadIdx.x;
    int ebeg = bbase[b], eend = bbase[b + 1];
    int ecnt = eend - ebeg;
    if (tid < 128) ncnt[tid] = 0;
    __syncthreads();
    for (int i = tid; i < ecnt; i += 256) atomicAdd(&ncnt[(ebuf[ebeg + i] >> 22) & 127], 1);
    __syncthreads();
    int v = (tid < 128) ? ncnt[tid] : 0;
    if (tid < 128) nps[tid] = v;
    __syncthreads();
    for (int off = 1; off < 128; off <<= 1) {
        int u = (tid >= off && tid < 128) ? nps[tid - off] : 0;
        __syncthreads();
        if (tid < 128) nps[tid] += u;
        __syncthreads();
    }
    if (tid < 128) noff[tid] = nps[tid] - v;
    if (tid == 127) noff[128] = nps[127];
    __syncthreads();
    if (tid < 128) ncnt[tid] = 0;
    __syncthreads();
    for (int i = tid; i < ecnt; i += 256) {
        unsigned int p = ebuf[ebeg + i];
        int nl = (p >> 22) & 127;
        int r = atomicAdd(&ncnt[nl], 1);
        adj[ebeg + noff[nl] + r] = (int)(p & 0x3FFFFF);
    }
    for (int i = tid; i <= 128; i += 256) {
        int n = b * 128 + i;
        if (n <= N_NODES) row_ptr[n] = ebeg + noff[i];
    }
}

// ---------------- GEMM1: trans[N,256](bf16) = split3(h) x B1 ----------------
// 128 rows/block (8 groups), 8 waves = (rp 0..1) x (q 0..3); A h-blocks staged in LDS.
__global__ __launch_bounds__(512) void k_mm1(const ushort_t* __restrict__ AH,
        const ushort_t* __restrict__ B1, const float* __restrict__ bs1,
        ushort_t* __restrict__ trans) {
    __shared__ ushort_t lds[16896];   // union: A-stage 16384 shorts / epi 64*264
    int tid = threadIdx.x;
    size_t gb = (size_t)blockIdx.x * 8;
    #pragma unroll
    for (int it = 0; it < 4; ++it) {
        int f = it * 512 + tid;            // 0..2047 chunks of 16B
        int gl = f >> 8, part = (f >> 7) & 1, inner = f & 127;
        size_t srcp = ((gb + gl) * 32 + (part ? 24 : 8)) * 128 + (size_t)inner * 8;
        *(short8*)&lds[f * 8] = *(const short8*)&AH[srcp];
    }
    __syncthreads();
    int lane = tid & 63, wp = tid >> 6;
    int q = wp & 3, rp = wp >> 2;
    int g = lane >> 4, u = lane & 15;
    int n0 = blockIdx.x * 128;
    f32x4 zero = {0.f, 0.f, 0.f, 0.f};
    f32x4 acc[4][4];
    #pragma unroll
    for (int i = 0; i < 4; ++i)
        #pragma unroll
        for (int j = 0; j < 4; ++j) acc[i][j] = zero;
    #pragma unroll
    for (int s = 0; s < 6; ++s) {
        int part = (s == 2 || s == 3) ? 1 : 0;
        int lb = ((s & 1) ? 4 : 0) + g;
        short8 bfr[4], afr[4];
        #pragma unroll
        for (int ct = 0; ct < 4; ++ct)
            bfr[ct] = *(const short8*)&B1[((size_t)(s * 16 + q * 4 + ct) * 64 + g * 16 + u) * 8];
        #pragma unroll
        for (int rt = 0; rt < 4; ++rt) {
            int gl = rp * 4 + rt;
            afr[rt] = *(const short8*)&lds[((gl * 2 + part) * 8 + lb) * 128 + u * 8];
        }
        #pragma unroll
        for (int rt = 0; rt < 4; ++rt)
            #pragma unroll
            for (int ct = 0; ct < 4; ++ct)
                acc[rt][ct] = __builtin_amdgcn_mfma_f32_16x16x32_bf16(afr[rt], bfr[ct], acc[rt][ct], 0, 0, 0);
    }
    float bsv[4];
    #pragma unroll
    for (int ct = 0; ct < 4; ++ct) bsv[ct] = bs1[q * 64 + ct * 16 + u];
    #pragma unroll
    for (int h = 0; h < 2; ++h) {
        __syncthreads();
        if (rp == h) {
            #pragma unroll
            for (int rt = 0; rt < 4; ++rt)
                #pragma unroll
                for (int ct = 0; ct < 4; ++ct)
                    #pragma unroll
                    for (int j = 0; j < 4; ++j) {
                        int rl = rt * 16 + g * 4 + j;
                        lds[rl * 264 + q * 64 + ct * 16 + u] = f2bf(acc[rt][ct][j] + bsv[ct]);
                    }
        }
        __syncthreads();
        int rl = tid >> 3, seg = tid & 7;
        int n = n0 + h * 64 + rl;
        if (n < N_NODES) {
            #pragma unroll
            for (int i = 0; i < 4; ++i) {
                short8 v = *(const short8*)&lds[rl * 264 + seg * 32 + i * 8];
                *(short8*)&trans[(size_t)n * 256 + seg * 32 + i * 8] = v;
            }
        }
    }
}

// ---------------- GEMM2 + GRU: h = GRU(a,h), A staged in LDS, h updated in-place ----------------
__global__ __launch_bounds__(512) void k_mm2(ushort_t* __restrict__ AH,
        const ushort_t* __restrict__ B2, const float* __restrict__ bg2) {
    __shared__ ushort_t lds[32768];   // 64KB: 8 groups x 4096 shorts, exact AH image
    int tid = threadIdx.x;
    size_t base = (size_t)blockIdx.x * 8 * 4096;
    #pragma unroll
    for (int it = 0; it < 8; ++it) {
        int f = it * 512 + tid;            // 0..4095 chunks of 16B
        *(short8*)&lds[f * 8] = *(const short8*)&AH[base + (size_t)f * 8];
    }
    __syncthreads();
    int lane = tid & 63, wp = tid >> 6;
    int q = wp & 3, rp = wp >> 2;
    int g = lane >> 4, u = lane & 15;
    f32x4 zero = {0.f, 0.f, 0.f, 0.f};
    f32x4 acc[4][4];
    #pragma unroll
    for (int i = 0; i < 4; ++i)
        #pragma unroll
        for (int j = 0; j < 4; ++j) acc[i][j] = zero;
    const int bb2[12] = {0, 4, 8, 12, 16, 20, 24, 28, 0, 4, 8, 12};
    #pragma unroll
    for (int s = 0; s < 12; ++s) {
        short8 bfr[4], afr[4];
        #pragma unroll
        for (int ct = 0; ct < 4; ++ct)
            bfr[ct] = *(const short8*)&B2[((size_t)(s * 16 + q * 4 + ct) * 64 + g * 16 + u) * 8];
        #pragma unroll
        for (int rt = 0; rt < 4; ++rt) {
            int gl = rp * 4 + rt;
            afr[rt] = *(const short8*)&lds[(gl * 32 + bb2[s] + g) * 128 + u * 8];
        }
        #pragma unroll
        for (int rt = 0; rt < 4; ++rt)
            #pragma unroll
            for (int ct = 0; ct < 4; ++ct)
                acc[rt][ct] = __builtin_amdgcn_mfma_f32_16x16x32_bf16(afr[rt], bfr[ct], acc[rt][ct], 0, 0, 0);
    }
    __syncthreads();   // all LDS A-reads done before h-blocks are overwritten
    float bgv[4];
    #pragma unroll
    for (int ct = 0; ct < 4; ++ct) bgv[ct] = bg2[q * 64 + ct * 16 + u];
    int hid = q * 16 + u;
    int bhi = 8 + (hid >> 3), blo = 24 + (hid >> 3), el = hid & 7;
    #pragma unroll
    for (int rt = 0; rt < 4; ++rt) {
        int gl = rp * 4 + rt;
        #pragma unroll
        for (int j = 0; j < 4; ++j) {
            int uu = g * 4 + j;
            int shi = (gl * 32 + bhi) * 128 + uu * 8 + el;
            int slo = (gl * 32 + blo) * 128 + uu * 8 + el;
            float ho = bf2f(lds[shi]) + bf2f(lds[slo]);
            float rs  = acc[rt][0][j] + bgv[0];
            float zs  = acc[rt][1][j] + bgv[1];
            float inn = acc[rt][2][j] + bgv[2];
            float hnn = acc[rt][3][j] + bgv[3];
            float r = 1.f / (1.f + __expf(-rs));
            float z = 1.f / (1.f + __expf(-zs));
            float t = inn + r * hnn;
            float e2 = __expf(2.f * t);
            float nn = 1.f - 2.f / (e2 + 1.f);   // tanh(t), NaN-free
            float hnew = (1.f - z) * nn + z * ho;
            ushort_t hh = f2bf(hnew);
            lds[shi] = hh;
            lds[slo] = f2bf(hnew - bf2f(hh));
        }
    }
    __syncthreads();
    #pragma unroll
    for (int it = 0; it < 4; ++it) {
        int c = it * 512 + tid;            // 0..2047
        int gl = c >> 8, r = c & 255, bi = r >> 4, uu = r & 15;
        int blk = (bi < 8) ? (8 + bi) : (16 + bi);   // 8..15, 24..31
        int lofs = (gl * 32 + blk) * 128 + uu * 8;
        short8 v = *(const short8*)&lds[lofs];
        *(short8*)&AH[base + (size_t)lofs] = v;
    }
}

// ---------------- aggregation via CSR; 1 node per wave, unroll-8 MLP ----------------
__global__ __launch_bounds__(1024) void k_aggregate(const int* __restrict__ row_ptr,
        const int* __restrict__ adj, const ushort_t* __restrict__ trans,
        ushort_t* __restrict__ AH) {
    __shared__ float alds[16 * 72];
    int w = threadIdx.x >> 6, lane = threadIdx.x & 63;
    int grp = blockIdx.x;
    int n = grp * 16 + w;
    int beg = row_ptr[n], end = row_ptr[n + 1];
    float a0 = 0.f, a1 = 0.f, a2 = 0.f, a3 = 0.f;
    int i = beg;
    for (; i + 8 <= end; i += 8) {
        int pk[8];
        #pragma unroll
        for (int t = 0; t < 8; ++t) pk[t] = adj[i + t];
        float v[8];
        #pragma unroll
        for (int t = 0; t < 8; ++t)
            v[t] = bf2f(trans[(size_t)(pk[t] & 0xFFFFF) * 256 + (pk[t] >> 20) * 64 + lane]);
        a0 += v[0] + v[4]; a1 += v[1] + v[5]; a2 += v[2] + v[6]; a3 += v[3] + v[7];
    }
    for (; i + 2 <= end; i += 2) {
        int pk0 = adj[i], pk1 = adj[i + 1];
        a0 += bf2f(trans[(size_t)(pk0 & 0xFFFFF) * 256 + (pk0 >> 20) * 64 + lane]);
        a1 += bf2f(trans[(size_t)(pk1 & 0xFFFFF) * 256 + (pk1 >> 20) * 64 + lane]);
    }
    if (i < end) {
        int pk = adj[i];
        a2 += bf2f(trans[(size_t)(pk & 0xFFFFF) * 256 + (pk >> 20) * 64 + lane]);
    }
    alds[w * 72 + lane] = (a0 + a1) + (a2 + a3);
    __syncthreads();
    if (threadIdx.x < 256) {
        int bi = threadIdx.x >> 4, u = threadIdx.x & 15;
        int b8 = bi & 7;
        bool ishi = bi < 8;
        short8 ov;
        #pragma unroll
        for (int j = 0; j < 8; ++j) {
            float v = alds[u * 72 + b8 * 8 + j];
            ushort_t hh = f2bf(v);
            ov[j] = ishi ? (short)hh : (short)f2bf(v - bf2f(hh));
        }
        *(short8*)&AH[((size_t)grp * 32 + (ishi ? b8 : 16 + b8)) * 128 + u * 8] = ov;
    }
}

// ---------------- per-graph mean pooling ----------------
__global__ __launch_bounds__(256) void k_pool(const int* __restrict__ n2g,
        const ushort_t* __restrict__ AH, float* __restrict__ hg) {
    int gidx = blockIdx.x;
    int lo = 0, hi = N_NODES;
    while (lo < hi) { int mid = (lo + hi) >> 1; if (n2g[mid] < gidx) lo = mid + 1; else hi = mid; }
    int s = lo;
    hi = N_NODES;
    while (lo < hi) { int mid = (lo + hi) >> 1; if (n2g[mid] < gidx + 1) lo = mid + 1; else hi = mid; }
    int e = lo;
    int w = threadIdx.x >> 6, lane = threadIdx.x & 63;
    int bh = 8 + (lane >> 3), bl = 24 + (lane >> 3), el = lane & 7;
    float sum = 0.f;
    for (int n = s + w; n < e; n += 4) {
        size_t base = (size_t)(n >> 4) * 4096 + (size_t)(n & 15) * 8;
        sum += bf2f(AH[base + bh * 128 + el]) + bf2f(AH[base + bl * 128 + el]);
    }
    __shared__ float red[4][64];
    red[w][lane] = sum;
    __syncthreads();
    if (threadIdx.x < 64) {
        float tot = red[0][lane] + red[1][lane] + red[2][lane] + red[3][lane];
        float cnt = (float)(e - s);
        hg[gidx * 64 + lane] = tot / fmaxf(cnt, 1.f);
    }
}

// ---------------- classifier ----------------
__global__ __launch_bounds__(64) void k_cls(const float* __restrict__ hg,
        const float* __restrict__ W1, const float* __restrict__ b1,
        const float* __restrict__ W2, const float* __restrict__ b2,
        float* __restrict__ out) {
    int gidx = blockIdx.x;
    __shared__ float v[64];
    __shared__ float m[32];
    v[threadIdx.x] = hg[gidx * 64 + threadIdx.x];
    __syncthreads();
    if (threadIdx.x < 32) {
        float a = b1[threadIdx.x];
        #pragma unroll 8
        for (int k = 0; k < 64; ++k) a = fmaf(v[k], W1[threadIdx.x * 64 + k], a);
        m[threadIdx.x] = fmaxf(a, 0.f);
    }
    __syncthreads();
    if (threadIdx.x < 10) {
        float a = b2[threadIdx.x];
        #pragma unroll
        for (int j = 0; j < 32; ++j) a = fmaf(m[j], W2[threadIdx.x * 32 + j], a);
        out[gidx * 10 + threadIdx.x] = a;
    }
}

extern "C" void kernel_launch(void* const* d_in, const int* in_sizes, int n_in,
                              void* d_out, int out_size, void* d_ws, size_t ws_size,
                              hipStream_t stream) {
    const float* x    = (const float*)d_in[0];
    const int* src    = (const int*)d_in[1];
    const int* dst    = (const int*)d_in[2];
    const int* etype  = (const int*)d_in[3];
    const int* n2g    = (const int*)d_in[4];
    const float* W_in = (const float*)d_in[5];
    const float* b_in = (const float*)d_in[6];
    const float* We   = (const float*)d_in[7];
    const float* be   = (const float*)d_in[8];
    const float* W_ih = (const float*)d_in[9];
    const float* b_ih = (const float*)d_in[10];
    const float* W_hh = (const float*)d_in[11];
    const float* b_hh = (const float*)d_in[12];
    const float* W1   = (const float*)d_in[13];
    const float* b1   = (const float*)d_in[14];
    const float* W2   = (const float*)d_in[15];
    const float* b2   = (const float*)d_in[16];
    float* out = (float*)d_out;

    char* wsb = (char*)d_ws;
    size_t off = 0;
    auto alloc = [&](size_t bytes) -> void* {
        void* p = wsb + off;
        off += (bytes + 255) & ~(size_t)255;
        return p;
    };
    ushort_t* AH      = (ushort_t*)alloc((size_t)NGRP_PAD * 4096 * 2);   // 51.25 MB split [a|h]
    ushort_t* trans   = (ushort_t*)alloc((size_t)N_NODES * 256 * 2);     // 51.2 MB bf16
    int*      adj     = (int*)     alloc((size_t)N_EDGES * 4);
    unsigned int* ebuf = (unsigned int*)alloc((size_t)N_EDGES * 4);
    int*      row_ptr = (int*)     alloc((size_t)(N_NODES + 1) * 4);
    int*      bhist   = (int*)     alloc((size_t)NBKT * 4);
    int*      bbase   = (int*)     alloc((size_t)(NBKT + 1) * 4);
    int*      bcursor = (int*)     alloc((size_t)NBKT * 4);
    ushort_t* B1      = (ushort_t*)alloc((size_t)6 * 16 * 4 * 16 * 8 * 2);
    float*    bs1     = (float*)   alloc(256 * 4);
    ushort_t* B2      = (ushort_t*)alloc((size_t)12 * 16 * 4 * 16 * 8 * 2);
    float*    bg2     = (float*)   alloc(256 * 4);
    ushort_t* BIN     = (ushort_t*)alloc((size_t)24576 * 2);
    float*    hg      = (float*)   alloc(128 * 64 * 4);

    // zero padding groups so OOB-row reads are finite+deterministic
    hipMemsetAsync(AH + (size_t)NGRP * 4096, 0, (size_t)(NGRP_PAD - NGRP) * 4096 * 2, stream);

    hipLaunchKernelGGL(k_pack_b1, dim3(192), dim3(256), 0, stream, We, be, B1, bs1);
    hipLaunchKernelGGL(k_pack_b2, dim3(384), dim3(256), 0, stream, W_ih, b_ih, W_hh, b_hh, B2, bg2);
    hipLaunchKernelGGL(k_pack_bin, dim3(96), dim3(256), 0, stream, W_in, BIN);
    hipLaunchKernelGGL(k_linear_in, dim3((NGRP + 3) / 4), dim3(256), 0, stream, x, BIN, b_in, AH);

    // CSR build via two-level bucket sort
    hipMemsetAsync(bhist, 0, (size_t)NBKT * 4, stream);
    hipLaunchKernelGGL(k_bhist, dim3(256), dim3(256), 0, stream, dst, bhist);
    hipLaunchKernelGGL(k_bscan, dim3(1), dim3(1024), 0, stream, bhist, bbase, bcursor);
    hipLaunchKernelGGL(k_bscatter, dim3((N_EDGES + TILE_E - 1) / TILE_E), dim3(512), 0, stream,
                       src, dst, etype, bcursor, ebuf);
    hipLaunchKernelGGL(k_bcsr, dim3(NBKT), dim3(256), 0, stream, ebuf, bbase, adj, row_ptr);

    int gblk = NGRP_PAD / 8;   // 782
    for (int step = 0; step < STEPS; ++step) {
        hipLaunchKernelGGL(k_mm1, dim3(gblk), dim3(512), 0, stream, AH, B1, bs1, trans);
        hipLaunchKernelGGL(k_aggregate, dim3(NGRP), dim3(1024), 0, stream, row_ptr, adj, trans, AH);
        hipLaunchKernelGGL(k_mm2, dim3(gblk), dim3(512), 0, stream, AH, B2, bg2);
    }
    hipLaunchKernelGGL(k_pool, dim3(G_GRAPHS), dim3(256), 0, stream, n2g, AH, hg);
    hipLaunchKernelGGL(k_cls, dim3(G_GRAPHS), dim3(64), 0, stream, hg, W1, b1, W2, b2, out);
}

// Round 9
// 841.370 us; speedup vs baseline: 1.2838x; 1.0424x over previous
//
#include <hip/hip_runtime.h>
#include <hip/hip_bf16.h>
#include <math.h>

#define N_NODES 100000
#define N_EDGES 1000000
#define IN_DIM 128
#define HID 64
#define NET 4
#define STEPS 5
#define G_GRAPHS 128
#define LBL 10
#define NGRP 6250        // N_NODES / 16 (exact)
#define NGRP_PAD 6256    // multiple of 4 (k_step covers 4 groups = 64 nodes/block)
#define NBKT 1024        // CSR buckets of 128 nodes
#define TILE_E 8192      // edges per bscatter block

typedef __attribute__((ext_vector_type(8))) short short8;
typedef __attribute__((ext_vector_type(4))) float f32x4;
typedef unsigned short ushort_t;

__device__ inline ushort_t f2bf(float v) {
    __hip_bfloat16 b = __float2bfloat16(v);
    return __builtin_bit_cast(ushort_t, b);
}
__device__ inline float bf2f(ushort_t u) {
    __hip_bfloat16 b = __builtin_bit_cast(__hip_bfloat16, u);
    return __bfloat162float(b);
}

// AH layout: [group][32 blocks][16 rows(u)][8 elems(j)] shorts.
// blocks 8-15: h-hi, 24-31: h-lo (a-blocks 0-7/16-23 now unused). group stride 4096 shorts.
// hrow: [node][64] bf16 (hi part of h), row-major — the gather table. Double-buffered.

// ---------------- pack BC: We -> [24 sl][4 ct][64 lane][8 j] bf16 ----------------
// sl = p*8+ks ; k = ks*32+g*8+j ; (t,d) = (k>>6, k&63) ; col o = ct*16+u
// p0: Whi (for A-hi), p1: Whi (for A-lo), p2: Wlo (for A-hi)
__global__ void k_pack_bc(const float* __restrict__ We, ushort_t* __restrict__ BC) {
    int idx = blockIdx.x * blockDim.x + threadIdx.x;   // 49152
    if (idx >= 24 * 4 * 64 * 8) return;
    int j = idx & 7, lane = (idx >> 3) & 63, ct = (idx >> 9) & 3, sl = idx >> 11;
    int g = lane >> 4, u = lane & 15;
    int p = sl >> 3, ks = sl & 7;
    int k = ks * 32 + g * 8 + j;
    int t = k >> 6, d = k & 63;
    int o = ct * 16 + u;
    float val = We[t * 4096 + o * 64 + d];
    ushort_t hi = f2bf(val);
    BC[idx] = (p < 2) ? hi : f2bf(val - bf2f(hi));
}

// ---------------- pack B2: GRU fused weight -> [12][16][4][16][8] bf16 (unchanged) ----------------
__global__ void k_pack_b2(const float* __restrict__ W_ih, const float* __restrict__ b_ih,
                          const float* __restrict__ W_hh, const float* __restrict__ b_hh,
                          ushort_t* __restrict__ B2, float* __restrict__ bg2) {
    int idx = blockIdx.x * blockDim.x + threadIdx.x;
    if (idx >= 12 * 16 * 4 * 16 * 8) return;
    int j = idx & 7, u = (idx >> 3) & 15, g = (idx >> 7) & 3, ct = (idx >> 9) & 15, s = idx >> 13;
    int m = ct * 16 + u;
    int q = m >> 6, gate = (m >> 4) & 3, c = q * 16 + (m & 15);
    int k = (s & 3) * 32 + g * 8 + j;
    float val;
    if (gate == 0)      { int jr = c;        val = (k < 64) ? W_ih[jr * 64 + k] : W_hh[jr * 64 + k - 64]; }
    else if (gate == 1) { int jr = 64 + c;   val = (k < 64) ? W_ih[jr * 64 + k] : W_hh[jr * 64 + k - 64]; }
    else if (gate == 2) { int jr = 128 + c;  val = (k < 64) ? W_ih[jr * 64 + k] : 0.f; }
    else                { int jr = 128 + c;  val = (k < 64) ? 0.f : W_hh[jr * 64 + k - 64]; }
    ushort_t hi = f2bf(val);
    B2[idx] = (s < 8) ? hi : f2bf(val - bf2f(hi));
    if (s == 0 && g == 0 && j == 0) {
        float bv;
        if (gate == 0)      bv = b_ih[c] + b_hh[c];
        else if (gate == 1) bv = b_ih[64 + c] + b_hh[64 + c];
        else if (gate == 2) bv = b_ih[128 + c];
        else                bv = b_hh[128 + c];
        bg2[m] = bv;
    }
}

// ---------------- pack BIN: W_in -> [12 slices][4 ct][64 lane][8 j] bf16 ----------------
__global__ void k_pack_bin(const float* __restrict__ W_in, ushort_t* __restrict__ BIN) {
    int idx = blockIdx.x * blockDim.x + threadIdx.x; // 24576
    if (idx >= 24576) return;
    int j = idx & 7, lu = (idx >> 3) & 63, ct = (idx >> 9) & 3, s = idx >> 11;
    int g = lu >> 4, u = lu & 15;
    int m = ct * 16 + u;
    int k = (s & 3) * 32 + g * 8 + j;
    float val = W_in[m * 128 + k];
    ushort_t hi = f2bf(val);
    BIN[idx] = (s < 8) ? hi : f2bf(val - bf2f(hi));
}

// ---------------- h0 = x @ W_in.T + b_in via MFMA; writes AH h-blocks + hrow ----------------
__global__ __launch_bounds__(256) void k_linear_in(const float* __restrict__ x,
        const ushort_t* __restrict__ BIN, const float* __restrict__ b_in,
        ushort_t* __restrict__ AH, ushort_t* __restrict__ hrow) {
    __shared__ float hlds[4][16 * 68];
    int tid = threadIdx.x;
    int lane = tid & 63, wp = tid >> 6;
    int g = lane >> 4, u = lane & 15;
    int grp = blockIdx.x * 4 + wp;
    bool ok = grp < NGRP;
    int row = ok ? (grp * 16 + u) : 0;
    short8 xhi[4], xlo[4];
    #pragma unroll
    for (int ks = 0; ks < 4; ++ks) {
        const float* xp = &x[(size_t)row * 128 + ks * 32 + g * 8];
        float4 v0 = ok ? *(const float4*)xp : make_float4(0.f, 0.f, 0.f, 0.f);
        float4 v1 = ok ? *(const float4*)(xp + 4) : make_float4(0.f, 0.f, 0.f, 0.f);
        float vv[8] = {v0.x, v0.y, v0.z, v0.w, v1.x, v1.y, v1.z, v1.w};
        #pragma unroll
        for (int j = 0; j < 8; ++j) {
            ushort_t hh = f2bf(vv[j]);
            xhi[ks][j] = (short)hh;
            xlo[ks][j] = (short)f2bf(vv[j] - bf2f(hh));
        }
    }
    f32x4 zero = {0.f, 0.f, 0.f, 0.f};
    f32x4 acc[4] = {zero, zero, zero, zero};
    #pragma unroll
    for (int s = 0; s < 12; ++s) {
        int ks = s & 3;
        short8 af = (s < 4) ? xhi[ks] : (s < 8) ? xlo[ks] : xhi[ks];
        #pragma unroll
        for (int ct = 0; ct < 4; ++ct) {
            short8 bf = *(const short8*)&BIN[((size_t)(s * 4 + ct) * 64 + lane) * 8];
            acc[ct] = __builtin_amdgcn_mfma_f32_16x16x32_bf16(af, bf, acc[ct], 0, 0, 0);
        }
    }
    #pragma unroll
    for (int ct = 0; ct < 4; ++ct) {
        float bo = b_in[ct * 16 + u];
        #pragma unroll
        for (int j = 0; j < 4; ++j)
            hlds[wp][(g * 4 + j) * 68 + ct * 16 + u] = acc[ct][j] + bo;
    }
    __syncthreads();
    #pragma unroll
    for (int k = 0; k < 4; ++k) {
        int bi = g + 4 * k;      // 0..15
        short8 ov;
        #pragma unroll
        for (int j = 0; j < 8; ++j) {
            float v = hlds[wp][u * 68 + (bi & 7) * 8 + j];
            ushort_t hh = f2bf(v);
            ov[j] = (bi < 8) ? (short)hh : (short)f2bf(v - bf2f(hh));
        }
        int blk = (bi < 8) ? (8 + bi) : (24 + (bi - 8));
        if (ok) {
            *(short8*)&AH[((size_t)grp * 32 + blk) * 128 + u * 8] = ov;
            if (bi < 8)
                *(short8*)&hrow[((size_t)(grp * 16 + u)) * 64 + bi * 8] = ov;
        }
    }
}

// ================= CSR build: two-level bucket sort (unchanged from R8) =================
__global__ __launch_bounds__(256) void k_bhist(const int* __restrict__ dst,
        int* __restrict__ bhist) {
    __shared__ int h[NBKT];
    for (int i = threadIdx.x; i < NBKT; i += 256) h[i] = 0;
    __syncthreads();
    int idx = blockIdx.x * 256 + threadIdx.x;
    for (int e = idx; e < N_EDGES; e += 256 * 256) atomicAdd(&h[dst[e] >> 7], 1);
    __syncthreads();
    for (int i = threadIdx.x; i < NBKT; i += 256) {
        int c = h[i];
        if (c) atomicAdd(&bhist[i], c);
    }
}

__global__ __launch_bounds__(1024) void k_bscan(const int* __restrict__ bhist,
        int* __restrict__ bbase, int* __restrict__ bcursor) {
    __shared__ int ts[NBKT];
    int t = threadIdx.x;
    int v = bhist[t];
    ts[t] = v;
    __syncthreads();
    for (int off = 1; off < NBKT; off <<= 1) {
        int u = (t >= off) ? ts[t - off] : 0;
        __syncthreads();
        ts[t] += u;
        __syncthreads();
    }
    int excl = ts[t] - v;
    bbase[t] = excl;
    bcursor[t] = excl;
    if (t == NBKT - 1) bbase[NBKT] = ts[NBKT - 1];
}

__global__ __launch_bounds__(512) void k_bscatter(const int* __restrict__ src,
        const int* __restrict__ dst, const int* __restrict__ et,
        int* __restrict__ bcursor, unsigned int* __restrict__ ebuf) {
    __shared__ int hcnt[NBKT], loff[NBKT], gpos[NBKT], ps[512];
    __shared__ unsigned int stage[TILE_E];
    __shared__ unsigned short sbkt[TILE_E];
    int tid = threadIdx.x;
    int base = blockIdx.x * TILE_E;
    int tilecnt = min(TILE_E, N_EDGES - base);
    for (int i = tid; i < NBKT; i += 512) hcnt[i] = 0;
    __syncthreads();
    #pragma unroll
    for (int k = 0; k < TILE_E / 512; ++k) {
        int e = base + tid + k * 512;
        if (e < N_EDGES) atomicAdd(&hcnt[dst[e] >> 7], 1);
    }
    __syncthreads();
    int c0 = hcnt[tid * 2], c1 = hcnt[tid * 2 + 1];
    ps[tid] = c0 + c1;
    __syncthreads();
    for (int off = 1; off < 512; off <<= 1) {
        int u = (tid >= off) ? ps[tid - off] : 0;
        __syncthreads();
        ps[tid] += u;
        __syncthreads();
    }
    int ex = ps[tid] - (c0 + c1);
    loff[tid * 2] = ex;
    loff[tid * 2 + 1] = ex + c0;
    for (int b = tid; b < NBKT; b += 512) {
        int c = hcnt[b];
        gpos[b] = c ? atomicAdd(&bcursor[b], c) : 0;
    }
    __syncthreads();
    for (int i = tid; i < NBKT; i += 512) hcnt[i] = 0;
    __syncthreads();
    #pragma unroll
    for (int k = 0; k < TILE_E / 512; ++k) {
        int e = base + tid + k * 512;
        if (e < N_EDGES) {
            int d = dst[e];
            int b = d >> 7;
            int r = atomicAdd(&hcnt[b], 1);
            int lp = loff[b] + r;
            stage[lp] = (unsigned int)src[e] | ((unsigned int)et[e] << 20)
                      | ((unsigned int)(d & 127) << 22);
            sbkt[lp] = (unsigned short)b;
        }
    }
    __syncthreads();
    for (int i = tid; i < tilecnt; i += 512) {
        int b = sbkt[i];
        ebuf[gpos[b] + (i - loff[b])] = stage[i];
    }
}

__global__ __launch_bounds__(256) void k_bcsr(const unsigned int* __restrict__ ebuf,
        const int* __restrict__ bbase, int* __restrict__ adj, int* __restrict__ row_ptr) {
    __shared__ int ncnt[128], noff[129], nps[128];
    int b = blockIdx.x;
    int tid = threadIdx.x;
    int ebeg = bbase[b], eend = bbase[b + 1];
    int ecnt = eend - ebeg;
    if (tid < 128) ncnt[tid] = 0;
    __syncthreads();
    for (int i = tid; i < ecnt; i += 256) atomicAdd(&ncnt[(ebuf[ebeg + i] >> 22) & 127], 1);
    __syncthreads();
    int v = (tid < 128) ? ncnt[tid] : 0;
    if (tid < 128) nps[tid] = v;
    __syncthreads();
    for (int off = 1; off < 128; off <<= 1) {
        int u = (tid >= off && tid < 128) ? nps[tid - off] : 0;
        __syncthreads();
        if (tid < 128) nps[tid] += u;
        __syncthreads();
    }
    if (tid < 128) noff[tid] = nps[tid] - v;
    if (tid == 127) noff[128] = nps[127];
    __syncthreads();
    if (tid < 128) ncnt[tid] = 0;
    __syncthreads();
    for (int i = tid; i < ecnt; i += 256) {
        unsigned int p = ebuf[ebeg + i];
        int nl = (p >> 22) & 127;
        int r = atomicAdd(&ncnt[nl], 1);
        adj[ebeg + noff[nl] + r] = (int)(p & 0x3FFFFF);   // src | et<<20
    }
    for (int i = tid; i <= 128; i += 256) {
        int n = b * 128 + i;
        if (n <= N_NODES) row_ptr[n] = ebeg + noff[i];
    }
}

// ================= fused step: gather + transform + GRU =================
// 64 nodes/block (4 groups), 512 threads = 8 waves, grid NGRP_PAD/4.
// LDS union: aggf f32[64][260] (66560B) || { als ushort[64][136] (17408B) + hlds ushort[4*16*16*8] (16384B) }
// cnts f32[64][4] lives after aggf (outside the union).
__global__ __launch_bounds__(512) void k_step(const int* __restrict__ row_ptr,
        const int* __restrict__ adj, const ushort_t* __restrict__ hin,
        ushort_t* __restrict__ hout, ushort_t* __restrict__ AH,
        const ushort_t* __restrict__ BC, const float* __restrict__ be,
        const ushort_t* __restrict__ B2, const float* __restrict__ bg2) {
    __shared__ float smem[16896];                       // 67584 B
    float* aggf = smem;                                 // [64][260]
    float* cnts = smem + 16640;                         // [64][4]
    ushort_t* als  = (ushort_t*)smem;                   // [64][136]  (post-barrier alias)
    ushort_t* hlds = (ushort_t*)((char*)smem + 17408);  // [4][16][16][8]

    int tid = threadIdx.x, lane = tid & 63, wp = tid >> 6;
    int g = lane >> 4, u = lane & 15;
    int grp0 = blockIdx.x * 4;
    int nbase = grp0 * 16;

    // ---- Phase 1: per-etype gather of h (bf16 rows from hin) ----
    #pragma unroll 1
    for (int r = 0; r < 8; ++r) {
        int nl = wp * 8 + r;
        int n = nbase + nl;
        float a0 = 0.f, a1 = 0.f, a2 = 0.f, a3 = 0.f;
        float c0 = 0.f, c1 = 0.f, c2 = 0.f, c3 = 0.f;
        if (n < N_NODES) {
            int beg = row_ptr[n], end = row_ptr[n + 1];
            int i = beg;
            for (; i + 4 <= end; i += 4) {
                int p0 = adj[i], p1 = adj[i + 1], p2 = adj[i + 2], p3 = adj[i + 3];
                float v0 = bf2f(hin[(size_t)(p0 & 0xFFFFF) * 64 + lane]);
                float v1 = bf2f(hin[(size_t)(p1 & 0xFFFFF) * 64 + lane]);
                float v2 = bf2f(hin[(size_t)(p2 & 0xFFFFF) * 64 + lane]);
                float v3 = bf2f(hin[(size_t)(p3 & 0xFFFFF) * 64 + lane]);
                int e0 = p0 >> 20, e1 = p1 >> 20, e2 = p2 >> 20, e3 = p3 >> 20;
                a0 += (e0 == 0) ? v0 : 0.f; a1 += (e0 == 1) ? v0 : 0.f;
                a2 += (e0 == 2) ? v0 : 0.f; a3 += (e0 == 3) ? v0 : 0.f;
                a0 += (e1 == 0) ? v1 : 0.f; a1 += (e1 == 1) ? v1 : 0.f;
                a2 += (e1 == 2) ? v1 : 0.f; a3 += (e1 == 3) ? v1 : 0.f;
                a0 += (e2 == 0) ? v2 : 0.f; a1 += (e2 == 1) ? v2 : 0.f;
                a2 += (e2 == 2) ? v2 : 0.f; a3 += (e2 == 3) ? v2 : 0.f;
                a0 += (e3 == 0) ? v3 : 0.f; a1 += (e3 == 1) ? v3 : 0.f;
                a2 += (e3 == 2) ? v3 : 0.f; a3 += (e3 == 3) ? v3 : 0.f;
                c0 += ((e0 == 0) ? 1.f : 0.f) + ((e1 == 0) ? 1.f : 0.f) + ((e2 == 0) ? 1.f : 0.f) + ((e3 == 0) ? 1.f : 0.f);
                c1 += ((e0 == 1) ? 1.f : 0.f) + ((e1 == 1) ? 1.f : 0.f) + ((e2 == 1) ? 1.f : 0.f) + ((e3 == 1) ? 1.f : 0.f);
                c2 += ((e0 == 2) ? 1.f : 0.f) + ((e1 == 2) ? 1.f : 0.f) + ((e2 == 2) ? 1.f : 0.f) + ((e3 == 2) ? 1.f : 0.f);
                c3 += ((e0 == 3) ? 1.f : 0.f) + ((e1 == 3) ? 1.f : 0.f) + ((e2 == 3) ? 1.f : 0.f) + ((e3 == 3) ? 1.f : 0.f);
            }
            for (; i < end; ++i) {
                int pk = adj[i];
                float v = bf2f(hin[(size_t)(pk & 0xFFFFF) * 64 + lane]);
                int e = pk >> 20;
                a0 += (e == 0) ? v : 0.f; a1 += (e == 1) ? v : 0.f;
                a2 += (e == 2) ? v : 0.f; a3 += (e == 3) ? v : 0.f;
                c0 += (e == 0) ? 1.f : 0.f; c1 += (e == 1) ? 1.f : 0.f;
                c2 += (e == 2) ? 1.f : 0.f; c3 += (e == 3) ? 1.f : 0.f;
            }
        }
        aggf[nl * 260 +   0 + lane] = a0;
        aggf[nl * 260 +  64 + lane] = a1;
        aggf[nl * 260 + 128 + lane] = a2;
        aggf[nl * 260 + 192 + lane] = a3;
        if (lane == 0) {
            cnts[nl * 4 + 0] = c0; cnts[nl * 4 + 1] = c1;
            cnts[nl * 4 + 2] = c2; cnts[nl * 4 + 3] = c3;
        }
    }
    __syncthreads();

    // ---- Phase 2: MFMA1  a[64][64] = split3(agg[64][256]) x BC ----
    // 8 waves = rp1(0..3 row-tiles) x cq(0..1 col-halves); per wave 2 col-tiles (ct)
    int rp1 = wp >> 1, cq = wp & 1;
    f32x4 zero = {0.f, 0.f, 0.f, 0.f};
    f32x4 acc1[2] = {zero, zero};
    #pragma unroll
    for (int ks = 0; ks < 8; ++ks) {
        const float* ap = &aggf[(rp1 * 16 + u) * 260 + ks * 32 + g * 8];
        f32x4 x0 = *(const f32x4*)ap;
        f32x4 x1 = *(const f32x4*)(ap + 4);
        short8 ahi, alo;
        #pragma unroll
        for (int j = 0; j < 4; ++j) {
            ushort_t hh = f2bf(x0[j]);
            ahi[j] = (short)hh; alo[j] = (short)f2bf(x0[j] - bf2f(hh));
            ushort_t hh2 = f2bf(x1[j]);
            ahi[4 + j] = (short)hh2; alo[4 + j] = (short)f2bf(x1[j] - bf2f(hh2));
        }
        #pragma unroll
        for (int p = 0; p < 3; ++p) {
            short8 af = (p == 1) ? alo : ahi;
            #pragma unroll
            for (int ct = 0; ct < 2; ++ct) {
                short8 bf = *(const short8*)&BC[((size_t)((p * 8 + ks) * 4 + cq * 2 + ct) * 64 + lane) * 8];
                acc1[ct] = __builtin_amdgcn_mfma_f32_16x16x32_bf16(af, bf, acc1[ct], 0, 0, 0);
            }
        }
    }
    __syncthreads();   // aggf dead; als/hlds region live (cnts survives outside union)

    // ---- Phase 3a: write a (hi/lo) to als with per-etype count x bias; stage own h to hlds ----
    {
        float beL[2][4];
        #pragma unroll
        for (int ct = 0; ct < 2; ++ct)
            #pragma unroll
            for (int t = 0; t < 4; ++t)
                beL[ct][t] = be[t * 64 + cq * 32 + ct * 16 + u];
        #pragma unroll
        for (int j = 0; j < 4; ++j) {
            int row = rp1 * 16 + g * 4 + j;
            f32x4 cn = *(const f32x4*)&cnts[row * 4];
            #pragma unroll
            for (int ct = 0; ct < 2; ++ct) {
                float v = acc1[ct][j] + cn[0] * beL[ct][0] + cn[1] * beL[ct][1]
                                      + cn[2] * beL[ct][2] + cn[3] * beL[ct][3];
                int col = cq * 32 + ct * 16 + u;
                ushort_t hh = f2bf(v);
                als[row * 136 + col] = hh;
                als[row * 136 + 64 + col] = f2bf(v - bf2f(hh));
            }
        }
    }
    #pragma unroll
    for (int it = 0; it < 2; ++it) {
        int c = it * 512 + tid;            // 0..1023
        int gl = c >> 8, r = c & 255, bi = r >> 4, uu = r & 15;
        int blk = (bi < 8) ? (8 + bi) : (24 + (bi - 8));
        *(short8*)&hlds[((gl * 16 + bi) * 16 + uu) * 8] =
            *(const short8*)&AH[((size_t)(grp0 + gl) * 32 + blk) * 128 + uu * 8];
    }
    __syncthreads();

    // ---- Phase 3b: MFMA2 gates[64][256] = split3([a|h]) x B2 ----
    // 8 waves = rp2(0..1, 32 rows) x q(0..3, 64-col quadrants); acc[2][4]
    int q = wp & 3, rp2 = wp >> 2;
    f32x4 acc2[2][4];
    #pragma unroll
    for (int i = 0; i < 2; ++i)
        #pragma unroll
        for (int j = 0; j < 4; ++j) acc2[i][j] = zero;
    #pragma unroll
    for (int s = 0; s < 12; ++s) {
        int p2 = s >> 2, ks2 = s & 3;
        short8 bfr[4], afr[2];
        #pragma unroll
        for (int ct = 0; ct < 4; ++ct)
            bfr[ct] = *(const short8*)&B2[((size_t)(s * 16 + q * 4 + ct) * 64 + g * 16 + u) * 8];
        #pragma unroll
        for (int rt = 0; rt < 2; ++rt) {
            int row = rp2 * 32 + rt * 16 + u;
            if (ks2 < 2) {
                int base = ((p2 == 1) ? 64 : 0) + ks2 * 32 + g * 8;
                afr[rt] = *(const short8*)&als[row * 136 + base];
            } else {
                int part = (p2 == 1) ? 1 : 0;
                int gl = rp2 * 2 + rt;
                int bi = part * 8 + (ks2 - 2) * 4 + g;
                afr[rt] = *(const short8*)&hlds[((gl * 16 + bi) * 16 + u) * 8];
            }
        }
        #pragma unroll
        for (int rt = 0; rt < 2; ++rt)
            #pragma unroll
            for (int ct = 0; ct < 4; ++ct)
                acc2[rt][ct] = __builtin_amdgcn_mfma_f32_16x16x32_bf16(afr[rt], bfr[ct], acc2[rt][ct], 0, 0, 0);
    }
    __syncthreads();   // all als/hlds MFMA reads done before hlds h-update

    // ---- Phase 4: GRU elementwise, update hlds in place (wave-disjoint columns) ----
    {
        float bgv[4];
        #pragma unroll
        for (int ct = 0; ct < 4; ++ct) bgv[ct] = bg2[q * 64 + ct * 16 + u];
        int hid = q * 16 + u;
        #pragma unroll
        for (int rt = 0; rt < 2; ++rt) {
            int gl = rp2 * 2 + rt;
            #pragma unroll
            for (int j = 0; j < 4; ++j) {
                int uu = g * 4 + j;
                int shi = ((gl * 16 + (hid >> 3)) * 16 + uu) * 8 + (hid & 7);
                int slo = ((gl * 16 + 8 + (hid >> 3)) * 16 + uu) * 8 + (hid & 7);
                float ho = bf2f(hlds[shi]) + bf2f(hlds[slo]);
                float rs  = acc2[rt][0][j] + bgv[0];
                float zs  = acc2[rt][1][j] + bgv[1];
                float inn = acc2[rt][2][j] + bgv[2];
                float hnn = acc2[rt][3][j] + bgv[3];
                float rr = 1.f / (1.f + __expf(-rs));
                float zz = 1.f / (1.f + __expf(-zs));
                float t = inn + rr * hnn;
                float e2 = __expf(2.f * t);
                float nn = 1.f - 2.f / (e2 + 1.f);
                float hnew = (1.f - zz) * nn + zz * ho;
                ushort_t hh = f2bf(hnew);
                hlds[shi] = hh;
                hlds[slo] = f2bf(hnew - bf2f(hh));
            }
        }
    }
    __syncthreads();

    // ---- pack-out: hlds -> AH h-blocks + hout (bf16-hi row-major) ----
    #pragma unroll
    for (int it = 0; it < 2; ++it) {
        int c = it * 512 + tid;            // 0..1023
        int gl = c >> 8, r = c & 255, bi = r >> 4, uu = r & 15;
        short8 v = *(const short8*)&hlds[((gl * 16 + bi) * 16 + uu) * 8];
        int blk = (bi < 8) ? (8 + bi) : (24 + (bi - 8));
        *(short8*)&AH[((size_t)(grp0 + gl) * 32 + blk) * 128 + uu * 8] = v;
        if (bi < 8)
            *(short8*)&hout[((size_t)((grp0 + gl) * 16 + uu)) * 64 + bi * 8] = v;
    }
}

// ---------------- per-graph mean pooling (reads AH h-blocks) ----------------
__global__ __launch_bounds__(256) void k_pool(const int* __restrict__ n2g,
        const ushort_t* __restrict__ AH, float* __restrict__ hg) {
    int gidx = blockIdx.x;
    int lo = 0, hi = N_NODES;
    while (lo < hi) { int mid = (lo + hi) >> 1; if (n2g[mid] < gidx) lo = mid + 1; else hi = mid; }
    int s = lo;
    hi = N_NODES;
    while (lo < hi) { int mid = (lo + hi) >> 1; if (n2g[mid] < gidx + 1) lo = mid + 1; else hi = mid; }
    int e = lo;
    int w = threadIdx.x >> 6, lane = threadIdx.x & 63;
    int bh = 8 + (lane >> 3), bl = 24 + (lane >> 3), el = lane & 7;
    float sum = 0.f;
    for (int n = s + w; n < e; n += 4) {
        size_t base = (size_t)(n >> 4) * 4096 + (size_t)(n & 15) * 8;
        sum += bf2f(AH[base + bh * 128 + el]) + bf2f(AH[base + bl * 128 + el]);
    }
    __shared__ float red[4][64];
    red[w][lane] = sum;
    __syncthreads();
    if (threadIdx.x < 64) {
        float tot = red[0][lane] + red[1][lane] + red[2][lane] + red[3][lane];
        float cnt = (float)(e - s);
        hg[gidx * 64 + lane] = tot / fmaxf(cnt, 1.f);
    }
}

// ---------------- classifier ----------------
__global__ __launch_bounds__(64) void k_cls(const float* __restrict__ hg,
        const float* __restrict__ W1, const float* __restrict__ b1,
        const float* __restrict__ W2, const float* __restrict__ b2,
        float* __restrict__ out) {
    int gidx = blockIdx.x;
    __shared__ float v[64];
    __shared__ float m[32];
    v[threadIdx.x] = hg[gidx * 64 + threadIdx.x];
    __syncthreads();
    if (threadIdx.x < 32) {
        float a = b1[threadIdx.x];
        #pragma unroll 8
        for (int k = 0; k < 64; ++k) a = fmaf(v[k], W1[threadIdx.x * 64 + k], a);
        m[threadIdx.x] = fmaxf(a, 0.f);
    }
    __syncthreads();
    if (threadIdx.x < 10) {
        float a = b2[threadIdx.x];
        #pragma unroll
        for (int j = 0; j < 32; ++j) a = fmaf(m[j], W2[threadIdx.x * 32 + j], a);
        out[gidx * 10 + threadIdx.x] = a;
    }
}

extern "C" void kernel_launch(void* const* d_in, const int* in_sizes, int n_in,
                              void* d_out, int out_size, void* d_ws, size_t ws_size,
                              hipStream_t stream) {
    const float* x    = (const float*)d_in[0];
    const int* src    = (const int*)d_in[1];
    const int* dst    = (const int*)d_in[2];
    const int* etype  = (const int*)d_in[3];
    const int* n2g    = (const int*)d_in[4];
    const float* W_in = (const float*)d_in[5];
    const float* b_in = (const float*)d_in[6];
    const float* We   = (const float*)d_in[7];
    const float* be   = (const float*)d_in[8];
    const float* W_ih = (const float*)d_in[9];
    const float* b_ih = (const float*)d_in[10];
    const float* W_hh = (const float*)d_in[11];
    const float* b_hh = (const float*)d_in[12];
    const float* W1   = (const float*)d_in[13];
    const float* b1   = (const float*)d_in[14];
    const float* W2   = (const float*)d_in[15];
    const float* b2   = (const float*)d_in[16];
    float* out = (float*)d_out;

    char* wsb = (char*)d_ws;
    size_t off = 0;
    auto alloc = [&](size_t bytes) -> void* {
        void* p = wsb + off;
        off += (bytes + 255) & ~(size_t)255;
        return p;
    };
    ushort_t* AH      = (ushort_t*)alloc((size_t)NGRP_PAD * 4096 * 2);   // 51.25 MB
    ushort_t* hrowA   = (ushort_t*)alloc((size_t)NGRP_PAD * 16 * 64 * 2); // 12.8 MB
    ushort_t* hrowB   = (ushort_t*)alloc((size_t)NGRP_PAD * 16 * 64 * 2); // 12.8 MB
    int*      adj     = (int*)     alloc((size_t)N_EDGES * 4);
    unsigned int* ebuf = (unsigned int*)alloc((size_t)N_EDGES * 4);
    int*      row_ptr = (int*)     alloc((size_t)(N_NODES + 1) * 4);
    int*      bhist   = (int*)     alloc((size_t)NBKT * 4);
    int*      bbase   = (int*)     alloc((size_t)(NBKT + 1) * 4);
    int*      bcursor = (int*)     alloc((size_t)NBKT * 4);
    ushort_t* B2      = (ushort_t*)alloc((size_t)12 * 16 * 4 * 16 * 8 * 2);
    float*    bg2     = (float*)   alloc(256 * 4);
    ushort_t* BIN     = (ushort_t*)alloc((size_t)24576 * 2);
    ushort_t* BC      = (ushort_t*)alloc((size_t)24 * 4 * 64 * 8 * 2);    // 96 KB
    float*    hg      = (float*)   alloc(128 * 64 * 4);

    // zero AH padding groups (deterministic padded-row math)
    hipMemsetAsync(AH + (size_t)NGRP * 4096, 0, (size_t)(NGRP_PAD - NGRP) * 4096 * 2, stream);

    hipLaunchKernelGGL(k_pack_b2, dim3(384), dim3(256), 0, stream, W_ih, b_ih, W_hh, b_hh, B2, bg2);
    hipLaunchKernelGGL(k_pack_bin, dim3(96), dim3(256), 0, stream, W_in, BIN);
    hipLaunchKernelGGL(k_pack_bc, dim3(192), dim3(256), 0, stream, We, BC);
    hipLaunchKernelGGL(k_linear_in, dim3((NGRP + 3) / 4), dim3(256), 0, stream, x, BIN, b_in, AH, hrowA);

    // CSR build via two-level bucket sort
    hipMemsetAsync(bhist, 0, (size_t)NBKT * 4, stream);
    hipLaunchKernelGGL(k_bhist, dim3(256), dim3(256), 0, stream, dst, bhist);
    hipLaunchKernelGGL(k_bscan, dim3(1), dim3(1024), 0, stream, bhist, bbase, bcursor);
    hipLaunchKernelGGL(k_bscatter, dim3((N_EDGES + TILE_E - 1) / TILE_E), dim3(512), 0, stream,
                       src, dst, etype, bcursor, ebuf);
    hipLaunchKernelGGL(k_bcsr, dim3(NBKT), dim3(256), 0, stream, ebuf, bbase, adj, row_ptr);

    int sblk = NGRP_PAD / 4;   // 1564
    for (int step = 0; step < STEPS; ++step) {
        const ushort_t* hin = (step & 1) ? hrowB : hrowA;
        ushort_t* hout      = (step & 1) ? hrowA : hrowB;
        hipLaunchKernelGGL(k_step, dim3(sblk), dim3(512), 0, stream,
                           row_ptr, adj, hin, hout, AH, BC, be, B2, bg2);
    }
    hipLaunchKernelGGL(k_pool, dim3(G_GRAPHS), dim3(256), 0, stream, n2g, AH, hg);
    hipLaunchKernelGGL(k_cls, dim3(G_GRAPHS), dim3(64), 0, stream, hg, W1, b1, W2, b2, out);
}

// Round 10
// 825.554 us; speedup vs baseline: 1.3084x; 1.0192x over previous
//
#include <hip/hip_runtime.h>
#include <hip/hip_bf16.h>
#include <math.h>

#define N_NODES 100000
#define N_EDGES 1000000
#define IN_DIM 128
#define HID 64
#define NET 4
#define STEPS 5
#define G_GRAPHS 128
#define LBL 10
#define NGRP 6250        // N_NODES / 16 (exact; even -> no padding anywhere)
#define NBKT 1024        // CSR buckets of 128 nodes
#define TILE_E 8192      // edges per bscatter block

typedef __attribute__((ext_vector_type(8))) short short8;
typedef __attribute__((ext_vector_type(4))) float f32x4;
typedef unsigned short ushort_t;

__device__ inline ushort_t f2bf(float v) {
    __hip_bfloat16 b = __float2bfloat16(v);
    return __builtin_bit_cast(ushort_t, b);
}
__device__ inline float bf2f(ushort_t u) {
    __hip_bfloat16 b = __builtin_bit_cast(__hip_bfloat16, u);
    return __bfloat162float(b);
}

// AH layout: [group][32 blocks][16 rows(u)][8 elems(j)] shorts.
// blocks 8-15: h-hi, 24-31: h-lo. group stride 4096 shorts.
// hrow: [node][64] bf16 (hi part of h), row-major gather table, double-buffered.
// adj: per-(node,etype) segmented src lists; row_ptr2[n*4+t] = segment starts.

// ---------------- pack BC: We -> [24 sl][4 ct][64 lane][8 j] bf16 ----------------
// sl = p*8+ks ; k = ks*32+g*8+j ; (t,d) = (k>>6, k&63) ; col o = ct*16+u
// p0: Whi (A-hi), p1: Whi (A-lo), p2: Wlo (A-hi)
__global__ void k_pack_bc(const float* __restrict__ We, ushort_t* __restrict__ BC) {
    int idx = blockIdx.x * blockDim.x + threadIdx.x;   // 49152
    if (idx >= 24 * 4 * 64 * 8) return;
    int j = idx & 7, lane = (idx >> 3) & 63, ct = (idx >> 9) & 3, sl = idx >> 11;
    int g = lane >> 4, u = lane & 15;
    int p = sl >> 3, ks = sl & 7;
    int k = ks * 32 + g * 8 + j;
    int t = k >> 6, d = k & 63;
    int o = ct * 16 + u;
    float val = We[t * 4096 + o * 64 + d];
    ushort_t hi = f2bf(val);
    BC[idx] = (p < 2) ? hi : f2bf(val - bf2f(hi));
}

// ---------------- pack B2: GRU fused weight -> [12][16][4][16][8] bf16 ----------------
__global__ void k_pack_b2(const float* __restrict__ W_ih, const float* __restrict__ b_ih,
                          const float* __restrict__ W_hh, const float* __restrict__ b_hh,
                          ushort_t* __restrict__ B2, float* __restrict__ bg2) {
    int idx = blockIdx.x * blockDim.x + threadIdx.x;
    if (idx >= 12 * 16 * 4 * 16 * 8) return;
    int j = idx & 7, u = (idx >> 3) & 15, g = (idx >> 7) & 3, ct = (idx >> 9) & 15, s = idx >> 13;
    int m = ct * 16 + u;
    int q = m >> 6, gate = (m >> 4) & 3, c = q * 16 + (m & 15);
    int k = (s & 3) * 32 + g * 8 + j;
    float val;
    if (gate == 0)      { int jr = c;        val = (k < 64) ? W_ih[jr * 64 + k] : W_hh[jr * 64 + k - 64]; }
    else if (gate == 1) { int jr = 64 + c;   val = (k < 64) ? W_ih[jr * 64 + k] : W_hh[jr * 64 + k - 64]; }
    else if (gate == 2) { int jr = 128 + c;  val = (k < 64) ? W_ih[jr * 64 + k] : 0.f; }
    else                { int jr = 128 + c;  val = (k < 64) ? 0.f : W_hh[jr * 64 + k - 64]; }
    ushort_t hi = f2bf(val);
    B2[idx] = (s < 8) ? hi : f2bf(val - bf2f(hi));
    if (s == 0 && g == 0 && j == 0) {
        float bv;
        if (gate == 0)      bv = b_ih[c] + b_hh[c];
        else if (gate == 1) bv = b_ih[64 + c] + b_hh[64 + c];
        else if (gate == 2) bv = b_ih[128 + c];
        else                bv = b_hh[128 + c];
        bg2[m] = bv;
    }
}

// ---------------- pack BIN: W_in -> [12 slices][4 ct][64 lane][8 j] bf16 ----------------
__global__ void k_pack_bin(const float* __restrict__ W_in, ushort_t* __restrict__ BIN) {
    int idx = blockIdx.x * blockDim.x + threadIdx.x; // 24576
    if (idx >= 24576) return;
    int j = idx & 7, lu = (idx >> 3) & 63, ct = (idx >> 9) & 3, s = idx >> 11;
    int g = lu >> 4, u = lu & 15;
    int m = ct * 16 + u;
    int k = (s & 3) * 32 + g * 8 + j;
    float val = W_in[m * 128 + k];
    ushort_t hi = f2bf(val);
    BIN[idx] = (s < 8) ? hi : f2bf(val - bf2f(hi));
}

// ---------------- h0 = x @ W_in.T + b_in via MFMA; writes AH h-blocks + hrow ----------------
__global__ __launch_bounds__(256) void k_linear_in(const float* __restrict__ x,
        const ushort_t* __restrict__ BIN, const float* __restrict__ b_in,
        ushort_t* __restrict__ AH, ushort_t* __restrict__ hrow) {
    __shared__ float hlds[4][16 * 68];
    int tid = threadIdx.x;
    int lane = tid & 63, wp = tid >> 6;
    int g = lane >> 4, u = lane & 15;
    int grp = blockIdx.x * 4 + wp;
    bool ok = grp < NGRP;
    int row = ok ? (grp * 16 + u) : 0;
    short8 xhi[4], xlo[4];
    #pragma unroll
    for (int ks = 0; ks < 4; ++ks) {
        const float* xp = &x[(size_t)row * 128 + ks * 32 + g * 8];
        float4 v0 = ok ? *(const float4*)xp : make_float4(0.f, 0.f, 0.f, 0.f);
        float4 v1 = ok ? *(const float4*)(xp + 4) : make_float4(0.f, 0.f, 0.f, 0.f);
        float vv[8] = {v0.x, v0.y, v0.z, v0.w, v1.x, v1.y, v1.z, v1.w};
        #pragma unroll
        for (int j = 0; j < 8; ++j) {
            ushort_t hh = f2bf(vv[j]);
            xhi[ks][j] = (short)hh;
            xlo[ks][j] = (short)f2bf(vv[j] - bf2f(hh));
        }
    }
    f32x4 zero = {0.f, 0.f, 0.f, 0.f};
    f32x4 acc[4] = {zero, zero, zero, zero};
    #pragma unroll
    for (int s = 0; s < 12; ++s) {
        int ks = s & 3;
        short8 af = (s < 4) ? xhi[ks] : (s < 8) ? xlo[ks] : xhi[ks];
        #pragma unroll
        for (int ct = 0; ct < 4; ++ct) {
            short8 bf = *(const short8*)&BIN[((size_t)(s * 4 + ct) * 64 + lane) * 8];
            acc[ct] = __builtin_amdgcn_mfma_f32_16x16x32_bf16(af, bf, acc[ct], 0, 0, 0);
        }
    }
    #pragma unroll
    for (int ct = 0; ct < 4; ++ct) {
        float bo = b_in[ct * 16 + u];
        #pragma unroll
        for (int j = 0; j < 4; ++j)
            hlds[wp][(g * 4 + j) * 68 + ct * 16 + u] = acc[ct][j] + bo;
    }
    __syncthreads();
    #pragma unroll
    for (int k = 0; k < 4; ++k) {
        int bi = g + 4 * k;      // 0..15
        short8 ov;
        #pragma unroll
        for (int j = 0; j < 8; ++j) {
            float v = hlds[wp][u * 68 + (bi & 7) * 8 + j];
            ushort_t hh = f2bf(v);
            ov[j] = (bi < 8) ? (short)hh : (short)f2bf(v - bf2f(hh));
        }
        int blk = (bi < 8) ? (8 + bi) : (24 + (bi - 8));
        if (ok) {
            *(short8*)&AH[((size_t)grp * 32 + blk) * 128 + u * 8] = ov;
            if (bi < 8)
                *(short8*)&hrow[((size_t)(grp * 16 + u)) * 64 + bi * 8] = ov;
        }
    }
}

// ================= CSR build: two-level bucket sort, etype-segmented =================
__global__ __launch_bounds__(256) void k_bhist(const int* __restrict__ dst,
        int* __restrict__ bhist) {
    __shared__ int h[NBKT];
    for (int i = threadIdx.x; i < NBKT; i += 256) h[i] = 0;
    __syncthreads();
    int idx = blockIdx.x * 256 + threadIdx.x;
    for (int e = idx; e < N_EDGES; e += 256 * 256) atomicAdd(&h[dst[e] >> 7], 1);
    __syncthreads();
    for (int i = threadIdx.x; i < NBKT; i += 256) {
        int c = h[i];
        if (c) atomicAdd(&bhist[i], c);
    }
}

__global__ __launch_bounds__(1024) void k_bscan(const int* __restrict__ bhist,
        int* __restrict__ bbase, int* __restrict__ bcursor) {
    __shared__ int ts[NBKT];
    int t = threadIdx.x;
    int v = bhist[t];
    ts[t] = v;
    __syncthreads();
    for (int off = 1; off < NBKT; off <<= 1) {
        int u = (t >= off) ? ts[t - off] : 0;
        __syncthreads();
        ts[t] += u;
        __syncthreads();
    }
    int excl = ts[t] - v;
    bbase[t] = excl;
    bcursor[t] = excl;
    if (t == NBKT - 1) bbase[NBKT] = ts[NBKT - 1];
}

// payload: src(0..16) | et<<20 | (dst&127)<<22
__global__ __launch_bounds__(512) void k_bscatter(const int* __restrict__ src,
        const int* __restrict__ dst, const int* __restrict__ et,
        int* __restrict__ bcursor, unsigned int* __restrict__ ebuf) {
    __shared__ int hcnt[NBKT], loff[NBKT], gpos[NBKT], ps[512];
    __shared__ unsigned int stage[TILE_E];
    __shared__ unsigned short sbkt[TILE_E];
    int tid = threadIdx.x;
    int base = blockIdx.x * TILE_E;
    int tilecnt = min(TILE_E, N_EDGES - base);
    for (int i = tid; i < NBKT; i += 512) hcnt[i] = 0;
    __syncthreads();
    #pragma unroll
    for (int k = 0; k < TILE_E / 512; ++k) {
        int e = base + tid + k * 512;
        if (e < N_EDGES) atomicAdd(&hcnt[dst[e] >> 7], 1);
    }
    __syncthreads();
    int c0 = hcnt[tid * 2], c1 = hcnt[tid * 2 + 1];
    ps[tid] = c0 + c1;
    __syncthreads();
    for (int off = 1; off < 512; off <<= 1) {
        int u = (tid >= off) ? ps[tid - off] : 0;
        __syncthreads();
        ps[tid] += u;
        __syncthreads();
    }
    int ex = ps[tid] - (c0 + c1);
    loff[tid * 2] = ex;
    loff[tid * 2 + 1] = ex + c0;
    for (int b = tid; b < NBKT; b += 512) {
        int c = hcnt[b];
        gpos[b] = c ? atomicAdd(&bcursor[b], c) : 0;
    }
    __syncthreads();
    for (int i = tid; i < NBKT; i += 512) hcnt[i] = 0;
    __syncthreads();
    #pragma unroll
    for (int k = 0; k < TILE_E / 512; ++k) {
        int e = base + tid + k * 512;
        if (e < N_EDGES) {
            int d = dst[e];
            int b = d >> 7;
            int r = atomicAdd(&hcnt[b], 1);
            int lp = loff[b] + r;
            stage[lp] = (unsigned int)src[e] | ((unsigned int)et[e] << 20)
                      | ((unsigned int)(d & 127) << 22);
            sbkt[lp] = (unsigned short)b;
        }
    }
    __syncthreads();
    for (int i = tid; i < tilecnt; i += 512) {
        int b = sbkt[i];
        ebuf[gpos[b] + (i - loff[b])] = stage[i];
    }
}

// per-bucket: sort by (node,etype) -> adj segments + row_ptr2[n*4+t]
__global__ __launch_bounds__(256) void k_bcsr(const unsigned int* __restrict__ ebuf,
        const int* __restrict__ bbase, int* __restrict__ adj, int* __restrict__ row_ptr2) {
    __shared__ int ncnt[512], noff[513], ps[256];
    int b = blockIdx.x;
    int tid = threadIdx.x;
    int ebeg = bbase[b], eend = bbase[b + 1];
    int ecnt = eend - ebeg;
    ncnt[tid] = 0; ncnt[tid + 256] = 0;
    __syncthreads();
    for (int i = tid; i < ecnt; i += 256) {
        unsigned int p = ebuf[ebeg + i];
        int key = (int)((((p >> 22) & 127) << 2) | ((p >> 20) & 3));
        atomicAdd(&ncnt[key], 1);
    }
    __syncthreads();
    int c0 = ncnt[2 * tid], c1 = ncnt[2 * tid + 1];
    ps[tid] = c0 + c1;
    __syncthreads();
    for (int off = 1; off < 256; off <<= 1) {
        int u = (tid >= off) ? ps[tid - off] : 0;
        __syncthreads();
        ps[tid] += u;
        __syncthreads();
    }
    int ex = ps[tid] - (c0 + c1);
    noff[2 * tid] = ex;
    noff[2 * tid + 1] = ex + c0;
    if (tid == 255) noff[512] = ps[255];
    __syncthreads();
    ncnt[tid] = 0; ncnt[tid + 256] = 0;
    __syncthreads();
    for (int i = tid; i < ecnt; i += 256) {
        unsigned int p = ebuf[ebeg + i];
        int key = (int)((((p >> 22) & 127) << 2) | ((p >> 20) & 3));
        int r = atomicAdd(&ncnt[key], 1);
        adj[ebeg + noff[key] + r] = (int)(p & 0xFFFFF);   // src only
    }
    for (int k = tid; k < 512; k += 256)
        row_ptr2[b * 512 + k] = ebeg + noff[k];
    if (b == NBKT - 1 && tid == 0) row_ptr2[NBKT * 512] = eend;
}

// ================= fused step: segmented gather + transform + GRU =================
// 32 nodes/block (2 groups), 512 threads = 8 waves, grid NGRP/2 = 3125.
// LDS 33.8KB -> 4 blocks/CU. Union: aggf f32[32][260] || { als u16[32][136] + hlds u16[2][16][16][8] }
__global__ __launch_bounds__(512) void k_step(const int* __restrict__ row_ptr2,
        const int* __restrict__ adj, const ushort_t* __restrict__ hin,
        ushort_t* __restrict__ hout, ushort_t* __restrict__ AH,
        const ushort_t* __restrict__ BC, const float* __restrict__ be,
        const ushort_t* __restrict__ B2, const float* __restrict__ bg2) {
    __shared__ float smem[8448];                        // 33792 B
    float* aggf = smem;                                 // [32][260]
    float* cnts = smem + 8320;                          // [32][4] (outside union)
    ushort_t* als  = (ushort_t*)smem;                   // [32][136] post-barrier alias
    ushort_t* hlds = (ushort_t*)((char*)smem + 9216);   // [2][16][16][8]

    int tid = threadIdx.x, lane = tid & 63, wp = tid >> 6;
    int g = lane >> 4, u = lane & 15;
    int grp0 = blockIdx.x * 2;
    int nbase = grp0 * 16;

    // ---- Phase 1: segmented per-etype gather (pure load+add) ----
    #pragma unroll 1
    for (int r = 0; r < 4; ++r) {
        int nl = wp * 4 + r;
        int n = nbase + nl;
        const int* op = &row_ptr2[(size_t)n * 4];
        int o0 = op[0], o1 = op[1], o2 = op[2], o3 = op[3], o4 = op[4];
        #pragma unroll
        for (int t = 0; t < 4; ++t) {
            int i = (t == 0) ? o0 : (t == 1) ? o1 : (t == 2) ? o2 : o3;
            int e = (t == 0) ? o1 : (t == 1) ? o2 : (t == 2) ? o3 : o4;
            float s0 = 0.f, s1 = 0.f, s2 = 0.f, s3 = 0.f;
            for (; i + 4 <= e; i += 4) {
                int a0 = adj[i], a1 = adj[i + 1], a2 = adj[i + 2], a3 = adj[i + 3];
                s0 += bf2f(hin[(size_t)a0 * 64 + lane]);
                s1 += bf2f(hin[(size_t)a1 * 64 + lane]);
                s2 += bf2f(hin[(size_t)a2 * 64 + lane]);
                s3 += bf2f(hin[(size_t)a3 * 64 + lane]);
            }
            for (; i < e; ++i)
                s0 += bf2f(hin[(size_t)adj[i] * 64 + lane]);
            aggf[nl * 260 + t * 64 + lane] = (s0 + s1) + (s2 + s3);
        }
        if (lane == 0) {
            cnts[nl * 4 + 0] = (float)(o1 - o0);
            cnts[nl * 4 + 1] = (float)(o2 - o1);
            cnts[nl * 4 + 2] = (float)(o3 - o2);
            cnts[nl * 4 + 3] = (float)(o4 - o3);
        }
    }
    __syncthreads();

    // ---- Phase 2: MFMA1  a[32][64] = split3(agg[32][256]) x BC ----
    // 8 waves = rp1(0..1 row-tiles of 16) x cq(0..3 col-tiles of 16)
    int rp1 = wp >> 2, cq = wp & 3;
    f32x4 zero = {0.f, 0.f, 0.f, 0.f};
    f32x4 acc1 = zero;
    #pragma unroll
    for (int ks = 0; ks < 8; ++ks) {
        const float* ap = &aggf[(rp1 * 16 + u) * 260 + ks * 32 + g * 8];
        f32x4 x0 = *(const f32x4*)ap;
        f32x4 x1 = *(const f32x4*)(ap + 4);
        short8 ahi, alo;
        #pragma unroll
        for (int j = 0; j < 4; ++j) {
            ushort_t hh = f2bf(x0[j]);
            ahi[j] = (short)hh; alo[j] = (short)f2bf(x0[j] - bf2f(hh));
            ushort_t hh2 = f2bf(x1[j]);
            ahi[4 + j] = (short)hh2; alo[4 + j] = (short)f2bf(x1[j] - bf2f(hh2));
        }
        #pragma unroll
        for (int p = 0; p < 3; ++p) {
            short8 af = (p == 1) ? alo : ahi;
            short8 bf = *(const short8*)&BC[((size_t)((p * 8 + ks) * 4 + cq) * 64 + lane) * 8];
            acc1 = __builtin_amdgcn_mfma_f32_16x16x32_bf16(af, bf, acc1, 0, 0, 0);
        }
    }
    __syncthreads();   // aggf dead; als/hlds live below (cnts safe outside union)

    // ---- Phase 3a: a -> als (hi/lo) with per-etype count x bias; stage own h ----
    {
        float beL[4];
        #pragma unroll
        for (int t = 0; t < 4; ++t) beL[t] = be[t * 64 + cq * 16 + u];
        #pragma unroll
        for (int j = 0; j < 4; ++j) {
            int row = rp1 * 16 + g * 4 + j;
            f32x4 cn = *(const f32x4*)&cnts[row * 4];
            float v = acc1[j] + cn[0] * beL[0] + cn[1] * beL[1]
                              + cn[2] * beL[2] + cn[3] * beL[3];
            int col = cq * 16 + u;
            ushort_t hh = f2bf(v);
            als[row * 136 + col] = hh;
            als[row * 136 + 64 + col] = f2bf(v - bf2f(hh));
        }
    }
    {
        int c = tid;                       // 0..511 -> 2 grp x 16 bi x 16 uu
        int gl = c >> 8, rr = c & 255, bi = rr >> 4, uu = rr & 15;
        int blk = (bi < 8) ? (8 + bi) : (24 + (bi - 8));
        *(short8*)&hlds[((gl * 16 + bi) * 16 + uu) * 8] =
            *(const short8*)&AH[((size_t)(grp0 + gl) * 32 + blk) * 128 + uu * 8];
    }
    __syncthreads();

    // ---- Phase 3b: MFMA2 gates[32][256] = split3([a|h]) x B2 ----
    // 8 waves = rp2(0..1, group) x q(0..3, 64-col quadrant); acc2[4]
    int q = wp & 3, rp2 = wp >> 2;
    f32x4 acc2[4] = {zero, zero, zero, zero};
    #pragma unroll
    for (int s = 0; s < 12; ++s) {
        int p2 = s >> 2, ks2 = s & 3;
        short8 afr;
        if (ks2 < 2) {
            int base = ((p2 == 1) ? 64 : 0) + ks2 * 32 + g * 8;
            afr = *(const short8*)&als[(rp2 * 16 + u) * 136 + base];
        } else {
            int part = (p2 == 1) ? 1 : 0;
            int bi = part * 8 + (ks2 - 2) * 4 + g;
            afr = *(const short8*)&hlds[((rp2 * 16 + bi) * 16 + u) * 8];
        }
        #pragma unroll
        for (int ct = 0; ct < 4; ++ct) {
            short8 bfr = *(const short8*)&B2[((size_t)(s * 16 + q * 4 + ct) * 64 + g * 16 + u) * 8];
            acc2[ct] = __builtin_amdgcn_mfma_f32_16x16x32_bf16(afr, bfr, acc2[ct], 0, 0, 0);
        }
    }
    __syncthreads();   // all als/hlds reads done before hlds update

    // ---- Phase 4: GRU elementwise, update hlds in place ----
    {
        float bgv[4];
        #pragma unroll
        for (int ct = 0; ct < 4; ++ct) bgv[ct] = bg2[q * 64 + ct * 16 + u];
        int hid = q * 16 + u;
        #pragma unroll
        for (int j = 0; j < 4; ++j) {
            int uu = g * 4 + j;
            int shi = ((rp2 * 16 + (hid >> 3)) * 16 + uu) * 8 + (hid & 7);
            int slo = ((rp2 * 16 + 8 + (hid >> 3)) * 16 + uu) * 8 + (hid & 7);
            float ho = bf2f(hlds[shi]) + bf2f(hlds[slo]);
            float rs  = acc2[0][j] + bgv[0];
            float zs  = acc2[1][j] + bgv[1];
            float inn = acc2[2][j] + bgv[2];
            float hnn = acc2[3][j] + bgv[3];
            float rr = 1.f / (1.f + __expf(-rs));
            float zz = 1.f / (1.f + __expf(-zs));
            float t = inn + rr * hnn;
            float e2 = __expf(2.f * t);
            float nn = 1.f - 2.f / (e2 + 1.f);
            float hnew = (1.f - zz) * nn + zz * ho;
            ushort_t hh = f2bf(hnew);
            hlds[shi] = hh;
            hlds[slo] = f2bf(hnew - bf2f(hh));
        }
    }
    __syncthreads();

    // ---- pack-out: hlds -> AH h-blocks + hout ----
    {
        int c = tid;                       // 0..511
        int gl = c >> 8, rr = c & 255, bi = rr >> 4, uu = rr & 15;
        short8 v = *(const short8*)&hlds[((gl * 16 + bi) * 16 + uu) * 8];
        int blk = (bi < 8) ? (8 + bi) : (24 + (bi - 8));
        *(short8*)&AH[((size_t)(grp0 + gl) * 32 + blk) * 128 + uu * 8] = v;
        if (bi < 8)
            *(short8*)&hout[((size_t)((grp0 + gl) * 16 + uu)) * 64 + bi * 8] = v;
    }
}

// ---------------- per-graph mean pooling (reads AH h-blocks) ----------------
__global__ __launch_bounds__(256) void k_pool(const int* __restrict__ n2g,
        const ushort_t* __restrict__ AH, float* __restrict__ hg) {
    int gidx = blockIdx.x;
    int lo = 0, hi = N_NODES;
    while (lo < hi) { int mid = (lo + hi) >> 1; if (n2g[mid] < gidx) lo = mid + 1; else hi = mid; }
    int s = lo;
    hi = N_NODES;
    while (lo < hi) { int mid = (lo + hi) >> 1; if (n2g[mid] < gidx + 1) lo = mid + 1; else hi = mid; }
    int e = lo;
    int w = threadIdx.x >> 6, lane = threadIdx.x & 63;
    int bh = 8 + (lane >> 3), bl = 24 + (lane >> 3), el = lane & 7;
    float sum = 0.f;
    for (int n = s + w; n < e; n += 4) {
        size_t base = (size_t)(n >> 4) * 4096 + (size_t)(n & 15) * 8;
        sum += bf2f(AH[base + bh * 128 + el]) + bf2f(AH[base + bl * 128 + el]);
    }
    __shared__ float red[4][64];
    red[w][lane] = sum;
    __syncthreads();
    if (threadIdx.x < 64) {
        float tot = red[0][lane] + red[1][lane] + red[2][lane] + red[3][lane];
        float cnt = (float)(e - s);
        hg[gidx * 64 + lane] = tot / fmaxf(cnt, 1.f);
    }
}

// ---------------- classifier ----------------
__global__ __launch_bounds__(64) void k_cls(const float* __restrict__ hg,
        const float* __restrict__ W1, const float* __restrict__ b1,
        const float* __restrict__ W2, const float* __restrict__ b2,
        float* __restrict__ out) {
    int gidx = blockIdx.x;
    __shared__ float v[64];
    __shared__ float m[32];
    v[threadIdx.x] = hg[gidx * 64 + threadIdx.x];
    __syncthreads();
    if (threadIdx.x < 32) {
        float a = b1[threadIdx.x];
        #pragma unroll 8
        for (int k = 0; k < 64; ++k) a = fmaf(v[k], W1[threadIdx.x * 64 + k], a);
        m[threadIdx.x] = fmaxf(a, 0.f);
    }
    __syncthreads();
    if (threadIdx.x < 10) {
        float a = b2[threadIdx.x];
        #pragma unroll
        for (int j = 0; j < 32; ++j) a = fmaf(m[j], W2[threadIdx.x * 32 + j], a);
        out[gidx * 10 + threadIdx.x] = a;
    }
}

extern "C" void kernel_launch(void* const* d_in, const int* in_sizes, int n_in,
                              void* d_out, int out_size, void* d_ws, size_t ws_size,
                              hipStream_t stream) {
    const float* x    = (const float*)d_in[0];
    const int* src    = (const int*)d_in[1];
    const int* dst    = (const int*)d_in[2];
    const int* etype  = (const int*)d_in[3];
    const int* n2g    = (const int*)d_in[4];
    const float* W_in = (const float*)d_in[5];
    const float* b_in = (const float*)d_in[6];
    const float* We   = (const float*)d_in[7];
    const float* be   = (const float*)d_in[8];
    const float* W_ih = (const float*)d_in[9];
    const float* b_ih = (const float*)d_in[10];
    const float* W_hh = (const float*)d_in[11];
    const float* b_hh = (const float*)d_in[12];
    const float* W1   = (const float*)d_in[13];
    const float* b1   = (const float*)d_in[14];
    const float* W2   = (const float*)d_in[15];
    const float* b2   = (const float*)d_in[16];
    float* out = (float*)d_out;

    char* wsb = (char*)d_ws;
    size_t off = 0;
    auto alloc = [&](size_t bytes) -> void* {
        void* p = wsb + off;
        off += (bytes + 255) & ~(size_t)255;
        return p;
    };
    ushort_t* AH       = (ushort_t*)alloc((size_t)NGRP * 4096 * 2);       // 51.2 MB
    ushort_t* hrowA    = (ushort_t*)alloc((size_t)N_NODES * 64 * 2);      // 12.8 MB
    ushort_t* hrowB    = (ushort_t*)alloc((size_t)N_NODES * 64 * 2);      // 12.8 MB
    int*      adj      = (int*)     alloc((size_t)N_EDGES * 4);
    unsigned int* ebuf = (unsigned int*)alloc((size_t)N_EDGES * 4);
    int*      row_ptr2 = (int*)     alloc(((size_t)NBKT * 512 + 1) * 4);  // 2.1 MB
    int*      bhist    = (int*)     alloc((size_t)NBKT * 4);
    int*      bbase    = (int*)     alloc((size_t)(NBKT + 1) * 4);
    int*      bcursor  = (int*)     alloc((size_t)NBKT * 4);
    ushort_t* B2       = (ushort_t*)alloc((size_t)12 * 16 * 4 * 16 * 8 * 2);
    float*    bg2      = (float*)   alloc(256 * 4);
    ushort_t* BIN      = (ushort_t*)alloc((size_t)24576 * 2);
    ushort_t* BC       = (ushort_t*)alloc((size_t)24 * 4 * 64 * 8 * 2);   // 96 KB
    float*    hg       = (float*)   alloc(128 * 64 * 4);

    hipLaunchKernelGGL(k_pack_b2, dim3(384), dim3(256), 0, stream, W_ih, b_ih, W_hh, b_hh, B2, bg2);
    hipLaunchKernelGGL(k_pack_bin, dim3(96), dim3(256), 0, stream, W_in, BIN);
    hipLaunchKernelGGL(k_pack_bc, dim3(192), dim3(256), 0, stream, We, BC);
    hipLaunchKernelGGL(k_linear_in, dim3((NGRP + 3) / 4), dim3(256), 0, stream, x, BIN, b_in, AH, hrowA);

    // CSR build via two-level bucket sort, (node,etype)-segmented
    hipMemsetAsync(bhist, 0, (size_t)NBKT * 4, stream);
    hipLaunchKernelGGL(k_bhist, dim3(256), dim3(256), 0, stream, dst, bhist);
    hipLaunchKernelGGL(k_bscan, dim3(1), dim3(1024), 0, stream, bhist, bbase, bcursor);
    hipLaunchKernelGGL(k_bscatter, dim3((N_EDGES + TILE_E - 1) / TILE_E), dim3(512), 0, stream,
                       src, dst, etype, bcursor, ebuf);
    hipLaunchKernelGGL(k_bcsr, dim3(NBKT), dim3(256), 0, stream, ebuf, bbase, adj, row_ptr2);

    int sblk = NGRP / 2;   // 3125
    for (int step = 0; step < STEPS; ++step) {
        const ushort_t* hin = (step & 1) ? hrowB : hrowA;
        ushort_t* hout      = (step & 1) ? hrowA : hrowB;
        hipLaunchKernelGGL(k_step, dim3(sblk), dim3(512), 0, stream,
                           row_ptr2, adj, hin, hout, AH, BC, be, B2, bg2);
    }
    hipLaunchKernelGGL(k_pool, dim3(G_GRAPHS), dim3(256), 0, stream, n2g, AH, hg);
    hipLaunchKernelGGL(k_cls, dim3(G_GRAPHS), dim3(64), 0, stream, hg, W1, b1, W2, b2, out);
}

// Round 11
// 816.694 us; speedup vs baseline: 1.3226x; 1.0108x over previous
//
#include <hip/hip_runtime.h>
#include <hip/hip_bf16.h>
#include <math.h>

#define N_NODES 100000
#define N_EDGES 1000000
#define IN_DIM 128
#define HID 64
#define NET 4
#define STEPS 5
#define G_GRAPHS 128
#define LBL 10
#define NGRP 6250        // N_NODES / 16 (exact)
#define NBKT 1024        // CSR buckets of 128 nodes
#define TILE_E 8192      // edges per bscatter block

typedef __attribute__((ext_vector_type(8))) short short8;
typedef __attribute__((ext_vector_type(4))) float f32x4;
typedef unsigned short ushort_t;

__device__ inline ushort_t f2bf(float v) {
    __hip_bfloat16 b = __float2bfloat16(v);
    return __builtin_bit_cast(ushort_t, b);
}
__device__ inline float bf2f(ushort_t u) {
    __hip_bfloat16 b = __builtin_bit_cast(__hip_bfloat16, u);
    return __bfloat162float(b);
}

// h state: hrow (hi bf16) + lrow (lo bf16), each [node][64] row-major, double-buffered.
// adj: per-(node,etype) segmented src lists; row_ptr2[n*4+t] = segment starts.

// ---------------- pack BC: We -> [24 sl][4 ct][64 lane][8 j] bf16 ----------------
// sl = p*8+ks ; k = ks*32+g*8+j ; (t,d) = (k>>6, k&63) ; col o = ct*16+u
// p0: Whi (A-hi), p1: Whi (A-lo), p2: Wlo (A-hi)
__global__ void k_pack_bc(const float* __restrict__ We, ushort_t* __restrict__ BC) {
    int idx = blockIdx.x * blockDim.x + threadIdx.x;   // 49152
    if (idx >= 24 * 4 * 64 * 8) return;
    int j = idx & 7, lane = (idx >> 3) & 63, ct = (idx >> 9) & 3, sl = idx >> 11;
    int g = lane >> 4, u = lane & 15;
    int p = sl >> 3, ks = sl & 7;
    int k = ks * 32 + g * 8 + j;
    int t = k >> 6, d = k & 63;
    int o = ct * 16 + u;
    float val = We[t * 4096 + o * 64 + d];
    ushort_t hi = f2bf(val);
    BC[idx] = (p < 2) ? hi : f2bf(val - bf2f(hi));
}

// ---------------- pack B2: GRU fused weight -> [12][16][4][16][8] bf16 ----------------
__global__ void k_pack_b2(const float* __restrict__ W_ih, const float* __restrict__ b_ih,
                          const float* __restrict__ W_hh, const float* __restrict__ b_hh,
                          ushort_t* __restrict__ B2, float* __restrict__ bg2) {
    int idx = blockIdx.x * blockDim.x + threadIdx.x;
    if (idx >= 12 * 16 * 4 * 16 * 8) return;
    int j = idx & 7, u = (idx >> 3) & 15, g = (idx >> 7) & 3, ct = (idx >> 9) & 15, s = idx >> 13;
    int m = ct * 16 + u;
    int q = m >> 6, gate = (m >> 4) & 3, c = q * 16 + (m & 15);
    int k = (s & 3) * 32 + g * 8 + j;
    float val;
    if (gate == 0)      { int jr = c;        val = (k < 64) ? W_ih[jr * 64 + k] : W_hh[jr * 64 + k - 64]; }
    else if (gate == 1) { int jr = 64 + c;   val = (k < 64) ? W_ih[jr * 64 + k] : W_hh[jr * 64 + k - 64]; }
    else if (gate == 2) { int jr = 128 + c;  val = (k < 64) ? W_ih[jr * 64 + k] : 0.f; }
    else                { int jr = 128 + c;  val = (k < 64) ? 0.f : W_hh[jr * 64 + k - 64]; }
    ushort_t hi = f2bf(val);
    B2[idx] = (s < 8) ? hi : f2bf(val - bf2f(hi));
    if (s == 0 && g == 0 && j == 0) {
        float bv;
        if (gate == 0)      bv = b_ih[c] + b_hh[c];
        else if (gate == 1) bv = b_ih[64 + c] + b_hh[64 + c];
        else if (gate == 2) bv = b_ih[128 + c];
        else                bv = b_hh[128 + c];
        bg2[m] = bv;
    }
}

// ---------------- pack BIN: W_in -> [12 slices][4 ct][64 lane][8 j] bf16 ----------------
__global__ void k_pack_bin(const float* __restrict__ W_in, ushort_t* __restrict__ BIN) {
    int idx = blockIdx.x * blockDim.x + threadIdx.x; // 24576
    if (idx >= 24576) return;
    int j = idx & 7, lu = (idx >> 3) & 63, ct = (idx >> 9) & 3, s = idx >> 11;
    int g = lu >> 4, u = lu & 15;
    int m = ct * 16 + u;
    int k = (s & 3) * 32 + g * 8 + j;
    float val = W_in[m * 128 + k];
    ushort_t hi = f2bf(val);
    BIN[idx] = (s < 8) ? hi : f2bf(val - bf2f(hi));
}

// ---------------- h0 = x @ W_in.T + b_in via MFMA; writes hrow + lrow ----------------
__global__ __launch_bounds__(256) void k_linear_in(const float* __restrict__ x,
        const ushort_t* __restrict__ BIN, const float* __restrict__ b_in,
        ushort_t* __restrict__ hrow, ushort_t* __restrict__ lrow) {
    __shared__ float hlds[4][16 * 68];
    int tid = threadIdx.x;
    int lane = tid & 63, wp = tid >> 6;
    int g = lane >> 4, u = lane & 15;
    int grp = blockIdx.x * 4 + wp;
    bool ok = grp < NGRP;
    int row = ok ? (grp * 16 + u) : 0;
    short8 xhi[4], xlo[4];
    #pragma unroll
    for (int ks = 0; ks < 4; ++ks) {
        const float* xp = &x[(size_t)row * 128 + ks * 32 + g * 8];
        float4 v0 = ok ? *(const float4*)xp : make_float4(0.f, 0.f, 0.f, 0.f);
        float4 v1 = ok ? *(const float4*)(xp + 4) : make_float4(0.f, 0.f, 0.f, 0.f);
        float vv[8] = {v0.x, v0.y, v0.z, v0.w, v1.x, v1.y, v1.z, v1.w};
        #pragma unroll
        for (int j = 0; j < 8; ++j) {
            ushort_t hh = f2bf(vv[j]);
            xhi[ks][j] = (short)hh;
            xlo[ks][j] = (short)f2bf(vv[j] - bf2f(hh));
        }
    }
    f32x4 zero = {0.f, 0.f, 0.f, 0.f};
    f32x4 acc[4] = {zero, zero, zero, zero};
    #pragma unroll
    for (int s = 0; s < 12; ++s) {
        int ks = s & 3;
        short8 af = (s < 4) ? xhi[ks] : (s < 8) ? xlo[ks] : xhi[ks];
        #pragma unroll
        for (int ct = 0; ct < 4; ++ct) {
            short8 bf = *(const short8*)&BIN[((size_t)(s * 4 + ct) * 64 + lane) * 8];
            acc[ct] = __builtin_amdgcn_mfma_f32_16x16x32_bf16(af, bf, acc[ct], 0, 0, 0);
        }
    }
    #pragma unroll
    for (int ct = 0; ct < 4; ++ct) {
        float bo = b_in[ct * 16 + u];
        #pragma unroll
        for (int j = 0; j < 4; ++j)
            hlds[wp][(g * 4 + j) * 68 + ct * 16 + u] = acc[ct][j] + bo;
    }
    __syncthreads();
    #pragma unroll
    for (int k = 0; k < 4; ++k) {
        int bi = g + 4 * k;      // 0..15
        short8 ov;
        #pragma unroll
        for (int j = 0; j < 8; ++j) {
            float v = hlds[wp][u * 68 + (bi & 7) * 8 + j];
            ushort_t hh = f2bf(v);
            ov[j] = (bi < 8) ? (short)hh : (short)f2bf(v - bf2f(hh));
        }
        if (ok) {
            size_t base = (size_t)(grp * 16 + u) * 64;
            if (bi < 8) *(short8*)&hrow[base + bi * 8] = ov;
            else        *(short8*)&lrow[base + (bi - 8) * 8] = ov;
        }
    }
}

// ================= CSR build: two-level bucket sort, etype-segmented =================
__global__ __launch_bounds__(256) void k_bhist(const int* __restrict__ dst,
        int* __restrict__ bhist) {
    __shared__ int h[NBKT];
    for (int i = threadIdx.x; i < NBKT; i += 256) h[i] = 0;
    __syncthreads();
    int idx = blockIdx.x * 256 + threadIdx.x;
    for (int e = idx; e < N_EDGES; e += 256 * 256) atomicAdd(&h[dst[e] >> 7], 1);
    __syncthreads();
    for (int i = threadIdx.x; i < NBKT; i += 256) {
        int c = h[i];
        if (c) atomicAdd(&bhist[i], c);
    }
}

__global__ __launch_bounds__(1024) void k_bscan(const int* __restrict__ bhist,
        int* __restrict__ bbase, int* __restrict__ bcursor) {
    __shared__ int ts[NBKT];
    int t = threadIdx.x;
    int v = bhist[t];
    ts[t] = v;
    __syncthreads();
    for (int off = 1; off < NBKT; off <<= 1) {
        int u = (t >= off) ? ts[t - off] : 0;
        __syncthreads();
        ts[t] += u;
        __syncthreads();
    }
    int excl = ts[t] - v;
    bbase[t] = excl;
    bcursor[t] = excl;
    if (t == NBKT - 1) bbase[NBKT] = ts[NBKT - 1];
}

// payload: src(0..16) | et<<20 | (dst&127)<<22
__global__ __launch_bounds__(512) void k_bscatter(const int* __restrict__ src,
        const int* __restrict__ dst, const int* __restrict__ et,
        int* __restrict__ bcursor, unsigned int* __restrict__ ebuf) {
    __shared__ int hcnt[NBKT], loff[NBKT], gpos[NBKT], ps[512];
    __shared__ unsigned int stage[TILE_E];
    __shared__ unsigned short sbkt[TILE_E];
    int tid = threadIdx.x;
    int base = blockIdx.x * TILE_E;
    int tilecnt = min(TILE_E, N_EDGES - base);
    for (int i = tid; i < NBKT; i += 512) hcnt[i] = 0;
    __syncthreads();
    #pragma unroll
    for (int k = 0; k < TILE_E / 512; ++k) {
        int e = base + tid + k * 512;
        if (e < N_EDGES) atomicAdd(&hcnt[dst[e] >> 7], 1);
    }
    __syncthreads();
    int c0 = hcnt[tid * 2], c1 = hcnt[tid * 2 + 1];
    ps[tid] = c0 + c1;
    __syncthreads();
    for (int off = 1; off < 512; off <<= 1) {
        int u = (tid >= off) ? ps[tid - off] : 0;
        __syncthreads();
        ps[tid] += u;
        __syncthreads();
    }
    int ex = ps[tid] - (c0 + c1);
    loff[tid * 2] = ex;
    loff[tid * 2 + 1] = ex + c0;
    for (int b = tid; b < NBKT; b += 512) {
        int c = hcnt[b];
        gpos[b] = c ? atomicAdd(&bcursor[b], c) : 0;
    }
    __syncthreads();
    for (int i = tid; i < NBKT; i += 512) hcnt[i] = 0;
    __syncthreads();
    #pragma unroll
    for (int k = 0; k < TILE_E / 512; ++k) {
        int e = base + tid + k * 512;
        if (e < N_EDGES) {
            int d = dst[e];
            int b = d >> 7;
            int r = atomicAdd(&hcnt[b], 1);
            int lp = loff[b] + r;
            stage[lp] = (unsigned int)src[e] | ((unsigned int)et[e] << 20)
                      | ((unsigned int)(d & 127) << 22);
            sbkt[lp] = (unsigned short)b;
        }
    }
    __syncthreads();
    for (int i = tid; i < tilecnt; i += 512) {
        int b = sbkt[i];
        ebuf[gpos[b] + (i - loff[b])] = stage[i];
    }
}

// per-bucket: sort by (node,etype) -> adj segments + row_ptr2[n*4+t]
__global__ __launch_bounds__(256) void k_bcsr(const unsigned int* __restrict__ ebuf,
        const int* __restrict__ bbase, int* __restrict__ adj, int* __restrict__ row_ptr2) {
    __shared__ int ncnt[512], noff[513], ps[256];
    int b = blockIdx.x;
    int tid = threadIdx.x;
    int ebeg = bbase[b], eend = bbase[b + 1];
    int ecnt = eend - ebeg;
    ncnt[tid] = 0; ncnt[tid + 256] = 0;
    __syncthreads();
    for (int i = tid; i < ecnt; i += 256) {
        unsigned int p = ebuf[ebeg + i];
        int key = (int)((((p >> 22) & 127) << 2) | ((p >> 20) & 3));
        atomicAdd(&ncnt[key], 1);
    }
    __syncthreads();
    int c0 = ncnt[2 * tid], c1 = ncnt[2 * tid + 1];
    ps[tid] = c0 + c1;
    __syncthreads();
    for (int off = 1; off < 256; off <<= 1) {
        int u = (tid >= off) ? ps[tid - off] : 0;
        __syncthreads();
        ps[tid] += u;
        __syncthreads();
    }
    int ex = ps[tid] - (c0 + c1);
    noff[2 * tid] = ex;
    noff[2 * tid + 1] = ex + c0;
    if (tid == 255) noff[512] = ps[255];
    __syncthreads();
    ncnt[tid] = 0; ncnt[tid + 256] = 0;
    __syncthreads();
    for (int i = tid; i < ecnt; i += 256) {
        unsigned int p = ebuf[ebeg + i];
        int key = (int)((((p >> 22) & 127) << 2) | ((p >> 20) & 3));
        int r = atomicAdd(&ncnt[key], 1);
        adj[ebeg + noff[key] + r] = (int)(p & 0xFFFFF);   // src only
    }
    for (int k = tid; k < 512; k += 256)
        row_ptr2[b * 512 + k] = ebeg + noff[k];
    if (b == NBKT - 1 && tid == 0) row_ptr2[NBKT * 512] = eend;
}

// ================= fused step: 8-stream gather + transform + GRU =================
// 32 nodes/block (512 threads = 8 waves, 4 nodes/wave), grid NGRP/2 = 3125.
__global__ __launch_bounds__(512) void k_step(const int* __restrict__ row_ptr2,
        const int* __restrict__ adj, const ushort_t* __restrict__ hin,
        const ushort_t* __restrict__ lin, ushort_t* __restrict__ hout,
        ushort_t* __restrict__ lout,
        const ushort_t* __restrict__ BC, const float* __restrict__ be,
        const ushort_t* __restrict__ B2, const float* __restrict__ bg2) {
    __shared__ float smem[8448];                        // 33792 B
    float* aggf = smem;                                 // [32][260]
    float* cnts = smem + 8320;                          // [32][4] (outside union)
    ushort_t* als  = (ushort_t*)smem;                   // [32][136] post-barrier alias
    ushort_t* hlds = (ushort_t*)((char*)smem + 9216);   // [2][16][16][8]

    int tid = threadIdx.x, lane = tid & 63, wp = tid >> 6;
    int g = lane >> 4, u = lane & 15;
    int grp0 = blockIdx.x * 2;
    int nbase = grp0 * 16;

    // ---- Phase 1: 8-stream interleaved segmented gather (2 nodes x 4 etypes) ----
    #pragma unroll 1
    for (int pr = 0; pr < 2; ++pr) {
        int nl0 = wp * 4 + pr * 2;
        const int* op = &row_ptr2[(size_t)(nbase + nl0) * 4];
        int b0 = op[0], b1 = op[1], b2 = op[2], b3 = op[3], b4 = op[4];
        int b5 = op[5], b6 = op[6], b7 = op[7], b8 = op[8];
        int i0 = b0, i1 = b1, i2 = b2, i3 = b3, i4 = b4, i5 = b5, i6 = b6, i7 = b7;
        float s0 = 0.f, s1 = 0.f, s2 = 0.f, s3 = 0.f, s4 = 0.f, s5 = 0.f, s6 = 0.f, s7 = 0.f;
        bool c0 = i0 < b1, c1 = i1 < b2, c2 = i2 < b3, c3 = i3 < b4;
        bool c4 = i4 < b5, c5 = i5 < b6, c6 = i6 < b7, c7 = i7 < b8;
        int a0 = adj[c0 ? i0 : 0], a1 = adj[c1 ? i1 : 0];
        int a2 = adj[c2 ? i2 : 0], a3 = adj[c3 ? i3 : 0];
        int a4 = adj[c4 ? i4 : 0], a5 = adj[c5 ? i5 : 0];
        int a6 = adj[c6 ? i6 : 0], a7 = adj[c7 ? i7 : 0];
        while (c0 | c1 | c2 | c3 | c4 | c5 | c6 | c7) {
            ushort_t w0 = hin[(size_t)a0 * 64 + lane];
            ushort_t w1 = hin[(size_t)a1 * 64 + lane];
            ushort_t w2 = hin[(size_t)a2 * 64 + lane];
            ushort_t w3 = hin[(size_t)a3 * 64 + lane];
            ushort_t w4 = hin[(size_t)a4 * 64 + lane];
            ushort_t w5 = hin[(size_t)a5 * 64 + lane];
            ushort_t w6 = hin[(size_t)a6 * 64 + lane];
            ushort_t w7 = hin[(size_t)a7 * 64 + lane];
            i0 += c0; i1 += c1; i2 += c2; i3 += c3;
            i4 += c4; i5 += c5; i6 += c6; i7 += c7;
            s0 += c0 ? bf2f(w0) : 0.f;
            s1 += c1 ? bf2f(w1) : 0.f;
            s2 += c2 ? bf2f(w2) : 0.f;
            s3 += c3 ? bf2f(w3) : 0.f;
            s4 += c4 ? bf2f(w4) : 0.f;
            s5 += c5 ? bf2f(w5) : 0.f;
            s6 += c6 ? bf2f(w6) : 0.f;
            s7 += c7 ? bf2f(w7) : 0.f;
            c0 = i0 < b1; c1 = i1 < b2; c2 = i2 < b3; c3 = i3 < b4;
            c4 = i4 < b5; c5 = i5 < b6; c6 = i6 < b7; c7 = i7 < b8;
            a0 = adj[c0 ? i0 : 0]; a1 = adj[c1 ? i1 : 0];
            a2 = adj[c2 ? i2 : 0]; a3 = adj[c3 ? i3 : 0];
            a4 = adj[c4 ? i4 : 0]; a5 = adj[c5 ? i5 : 0];
            a6 = adj[c6 ? i6 : 0]; a7 = adj[c7 ? i7 : 0];
        }
        aggf[nl0 * 260 +   0 + lane] = s0;
        aggf[nl0 * 260 +  64 + lane] = s1;
        aggf[nl0 * 260 + 128 + lane] = s2;
        aggf[nl0 * 260 + 192 + lane] = s3;
        aggf[(nl0 + 1) * 260 +   0 + lane] = s4;
        aggf[(nl0 + 1) * 260 +  64 + lane] = s5;
        aggf[(nl0 + 1) * 260 + 128 + lane] = s6;
        aggf[(nl0 + 1) * 260 + 192 + lane] = s7;
        if (lane == 0) {
            cnts[nl0 * 4 + 0] = (float)(b1 - b0);
            cnts[nl0 * 4 + 1] = (float)(b2 - b1);
            cnts[nl0 * 4 + 2] = (float)(b3 - b2);
            cnts[nl0 * 4 + 3] = (float)(b4 - b3);
            cnts[(nl0 + 1) * 4 + 0] = (float)(b5 - b4);
            cnts[(nl0 + 1) * 4 + 1] = (float)(b6 - b5);
            cnts[(nl0 + 1) * 4 + 2] = (float)(b7 - b6);
            cnts[(nl0 + 1) * 4 + 3] = (float)(b8 - b7);
        }
    }
    __syncthreads();

    // ---- Phase 2: MFMA1  a[32][64] = split3(agg[32][256]) x BC ----
    int rp1 = wp >> 2, cq = wp & 3;
    f32x4 zero = {0.f, 0.f, 0.f, 0.f};
    f32x4 acc1 = zero;
    #pragma unroll
    for (int ks = 0; ks < 8; ++ks) {
        const float* ap = &aggf[(rp1 * 16 + u) * 260 + ks * 32 + g * 8];
        f32x4 x0 = *(const f32x4*)ap;
        f32x4 x1 = *(const f32x4*)(ap + 4);
        short8 ahi, alo;
        #pragma unroll
        for (int j = 0; j < 4; ++j) {
            ushort_t hh = f2bf(x0[j]);
            ahi[j] = (short)hh; alo[j] = (short)f2bf(x0[j] - bf2f(hh));
            ushort_t hh2 = f2bf(x1[j]);
            ahi[4 + j] = (short)hh2; alo[4 + j] = (short)f2bf(x1[j] - bf2f(hh2));
        }
        #pragma unroll
        for (int p = 0; p < 3; ++p) {
            short8 af = (p == 1) ? alo : ahi;
            short8 bf = *(const short8*)&BC[((size_t)((p * 8 + ks) * 4 + cq) * 64 + lane) * 8];
            acc1 = __builtin_amdgcn_mfma_f32_16x16x32_bf16(af, bf, acc1, 0, 0, 0);
        }
    }
    __syncthreads();   // aggf dead; als/hlds live below (cnts safe outside union)

    // ---- Phase 3a: a -> als (hi/lo) with per-etype count x bias; stage own h ----
    {
        float beL[4];
        #pragma unroll
        for (int t = 0; t < 4; ++t) beL[t] = be[t * 64 + cq * 16 + u];
        #pragma unroll
        for (int j = 0; j < 4; ++j) {
            int row = rp1 * 16 + g * 4 + j;
            f32x4 cn = *(const f32x4*)&cnts[row * 4];
            float v = acc1[j] + cn[0] * beL[0] + cn[1] * beL[1]
                              + cn[2] * beL[2] + cn[3] * beL[3];
            int col = cq * 16 + u;
            ushort_t hh = f2bf(v);
            als[row * 136 + col] = hh;
            als[row * 136 + 64 + col] = f2bf(v - bf2f(hh));
        }
    }
    {
        int c = tid;                       // 0..511 -> 2 grp x 16 bi x 16 uu
        int gl = c >> 8, rr = c & 255, bi = rr >> 4, uu = rr & 15;
        size_t base = (size_t)(nbase + gl * 16 + uu) * 64;
        short8 v = (bi < 8) ? *(const short8*)&hin[base + bi * 8]
                            : *(const short8*)&lin[base + (bi - 8) * 8];
        *(short8*)&hlds[((gl * 16 + bi) * 16 + uu) * 8] = v;
    }
    __syncthreads();

    // ---- Phase 3b: MFMA2 gates[32][256] = split3([a|h]) x B2 ----
    int q = wp & 3, rp2 = wp >> 2;
    f32x4 acc2[4] = {zero, zero, zero, zero};
    #pragma unroll
    for (int s = 0; s < 12; ++s) {
        int p2 = s >> 2, ks2 = s & 3;
        short8 afr;
        if (ks2 < 2) {
            int base = ((p2 == 1) ? 64 : 0) + ks2 * 32 + g * 8;
            afr = *(const short8*)&als[(rp2 * 16 + u) * 136 + base];
        } else {
            int part = (p2 == 1) ? 1 : 0;
            int bi = part * 8 + (ks2 - 2) * 4 + g;
            afr = *(const short8*)&hlds[((rp2 * 16 + bi) * 16 + u) * 8];
        }
        #pragma unroll
        for (int ct = 0; ct < 4; ++ct) {
            short8 bfr = *(const short8*)&B2[((size_t)(s * 16 + q * 4 + ct) * 64 + g * 16 + u) * 8];
            acc2[ct] = __builtin_amdgcn_mfma_f32_16x16x32_bf16(afr, bfr, acc2[ct], 0, 0, 0);
        }
    }
    __syncthreads();   // all als/hlds reads done before hlds update

    // ---- Phase 4: GRU elementwise, update hlds in place ----
    {
        float bgv[4];
        #pragma unroll
        for (int ct = 0; ct < 4; ++ct) bgv[ct] = bg2[q * 64 + ct * 16 + u];
        int hid = q * 16 + u;
        #pragma unroll
        for (int j = 0; j < 4; ++j) {
            int uu = g * 4 + j;
            int shi = ((rp2 * 16 + (hid >> 3)) * 16 + uu) * 8 + (hid & 7);
            int slo = ((rp2 * 16 + 8 + (hid >> 3)) * 16 + uu) * 8 + (hid & 7);
            float ho = bf2f(hlds[shi]) + bf2f(hlds[slo]);
            float rs  = acc2[0][j] + bgv[0];
            float zs  = acc2[1][j] + bgv[1];
            float inn = acc2[2][j] + bgv[2];
            float hnn = acc2[3][j] + bgv[3];
            float rr = 1.f / (1.f + __expf(-rs));
            float zz = 1.f / (1.f + __expf(-zs));
            float t = inn + rr * hnn;
            float e2 = __expf(2.f * t);
            float nn = 1.f - 2.f / (e2 + 1.f);
            float hnew = (1.f - zz) * nn + zz * ho;
            ushort_t hh = f2bf(hnew);
            hlds[shi] = hh;
            hlds[slo] = f2bf(hnew - bf2f(hh));
        }
    }
    __syncthreads();

    // ---- pack-out: hlds -> hout/lout rows ----
    {
        int c = tid;                       // 0..511
        int gl = c >> 8, rr = c & 255, bi = rr >> 4, uu = rr & 15;
        short8 v = *(const short8*)&hlds[((gl * 16 + bi) * 16 + uu) * 8];
        size_t base = (size_t)(nbase + gl * 16 + uu) * 64;
        if (bi < 8) *(short8*)&hout[base + bi * 8] = v;
        else        *(short8*)&lout[base + (bi - 8) * 8] = v;
    }
}

// ---------------- per-graph mean pooling (reads hrow+lrow) ----------------
__global__ __launch_bounds__(256) void k_pool(const int* __restrict__ n2g,
        const ushort_t* __restrict__ hrow, const ushort_t* __restrict__ lrow,
        float* __restrict__ hg) {
    int gidx = blockIdx.x;
    int lo = 0, hi = N_NODES;
    while (lo < hi) { int mid = (lo + hi) >> 1; if (n2g[mid] < gidx) lo = mid + 1; else hi = mid; }
    int s = lo;
    hi = N_NODES;
    while (lo < hi) { int mid = (lo + hi) >> 1; if (n2g[mid] < gidx + 1) lo = mid + 1; else hi = mid; }
    int e = lo;
    int w = threadIdx.x >> 6, lane = threadIdx.x & 63;
    float sum = 0.f;
    for (int n = s + w; n < e; n += 4)
        sum += bf2f(hrow[(size_t)n * 64 + lane]) + bf2f(lrow[(size_t)n * 64 + lane]);
    __shared__ float red[4][64];
    red[w][lane] = sum;
    __syncthreads();
    if (threadIdx.x < 64) {
        float tot = red[0][lane] + red[1][lane] + red[2][lane] + red[3][lane];
        float cnt = (float)(e - s);
        hg[gidx * 64 + lane] = tot / fmaxf(cnt, 1.f);
    }
}

// ---------------- classifier ----------------
__global__ __launch_bounds__(64) void k_cls(const float* __restrict__ hg,
        const float* __restrict__ W1, const float* __restrict__ b1,
        const float* __restrict__ W2, const float* __restrict__ b2,
        float* __restrict__ out) {
    int gidx = blockIdx.x;
    __shared__ float v[64];
    __shared__ float m[32];
    v[threadIdx.x] = hg[gidx * 64 + threadIdx.x];
    __syncthreads();
    if (threadIdx.x < 32) {
        float a = b1[threadIdx.x];
        #pragma unroll 8
        for (int k = 0; k < 64; ++k) a = fmaf(v[k], W1[threadIdx.x * 64 + k], a);
        m[threadIdx.x] = fmaxf(a, 0.f);
    }
    __syncthreads();
    if (threadIdx.x < 10) {
        float a = b2[threadIdx.x];
        #pragma unroll
        for (int j = 0; j < 32; ++j) a = fmaf(m[j], W2[threadIdx.x * 32 + j], a);
        out[gidx * 10 + threadIdx.x] = a;
    }
}

extern "C" void kernel_launch(void* const* d_in, const int* in_sizes, int n_in,
                              void* d_out, int out_size, void* d_ws, size_t ws_size,
                              hipStream_t stream) {
    const float* x    = (const float*)d_in[0];
    const int* src    = (const int*)d_in[1];
    const int* dst    = (const int*)d_in[2];
    const int* etype  = (const int*)d_in[3];
    const int* n2g    = (const int*)d_in[4];
    const float* W_in = (const float*)d_in[5];
    const float* b_in = (const float*)d_in[6];
    const float* We   = (const float*)d_in[7];
    const float* be   = (const float*)d_in[8];
    const float* W_ih = (const float*)d_in[9];
    const float* b_ih = (const float*)d_in[10];
    const float* W_hh = (const float*)d_in[11];
    const float* b_hh = (const float*)d_in[12];
    const float* W1   = (const float*)d_in[13];
    const float* b1   = (const float*)d_in[14];
    const float* W2   = (const float*)d_in[15];
    const float* b2   = (const float*)d_in[16];
    float* out = (float*)d_out;

    char* wsb = (char*)d_ws;
    size_t off = 0;
    auto alloc = [&](size_t bytes) -> void* {
        void* p = wsb + off;
        off += (bytes + 255) & ~(size_t)255;
        return p;
    };
    ushort_t* hrowA    = (ushort_t*)alloc((size_t)N_NODES * 64 * 2);      // 12.8 MB
    ushort_t* lrowA    = (ushort_t*)alloc((size_t)N_NODES * 64 * 2);      // 12.8 MB
    ushort_t* hrowB    = (ushort_t*)alloc((size_t)N_NODES * 64 * 2);      // 12.8 MB
    ushort_t* lrowB    = (ushort_t*)alloc((size_t)N_NODES * 64 * 2);      // 12.8 MB
    int*      adj      = (int*)     alloc((size_t)N_EDGES * 4);
    unsigned int* ebuf = (unsigned int*)alloc((size_t)N_EDGES * 4);
    int*      row_ptr2 = (int*)     alloc(((size_t)NBKT * 512 + 1) * 4);  // 2.1 MB
    int*      bhist    = (int*)     alloc((size_t)NBKT * 4);
    int*      bbase    = (int*)     alloc((size_t)(NBKT + 1) * 4);
    int*      bcursor  = (int*)     alloc((size_t)NBKT * 4);
    ushort_t* B2       = (ushort_t*)alloc((size_t)12 * 16 * 4 * 16 * 8 * 2);
    float*    bg2      = (float*)   alloc(256 * 4);
    ushort_t* BIN      = (ushort_t*)alloc((size_t)24576 * 2);
    ushort_t* BC       = (ushort_t*)alloc((size_t)24 * 4 * 64 * 8 * 2);   // 96 KB
    float*    hg       = (float*)   alloc(128 * 64 * 4);

    hipLaunchKernelGGL(k_pack_b2, dim3(384), dim3(256), 0, stream, W_ih, b_ih, W_hh, b_hh, B2, bg2);
    hipLaunchKernelGGL(k_pack_bin, dim3(96), dim3(256), 0, stream, W_in, BIN);
    hipLaunchKernelGGL(k_pack_bc, dim3(192), dim3(256), 0, stream, We, BC);
    hipLaunchKernelGGL(k_linear_in, dim3((NGRP + 3) / 4), dim3(256), 0, stream, x, BIN, b_in, hrowA, lrowA);

    // CSR build via two-level bucket sort, (node,etype)-segmented
    hipMemsetAsync(bhist, 0, (size_t)NBKT * 4, stream);
    hipLaunchKernelGGL(k_bhist, dim3(256), dim3(256), 0, stream, dst, bhist);
    hipLaunchKernelGGL(k_bscan, dim3(1), dim3(1024), 0, stream, bhist, bbase, bcursor);
    hipLaunchKernelGGL(k_bscatter, dim3((N_EDGES + TILE_E - 1) / TILE_E), dim3(512), 0, stream,
                       src, dst, etype, bcursor, ebuf);
    hipLaunchKernelGGL(k_bcsr, dim3(NBKT), dim3(256), 0, stream, ebuf, bbase, adj, row_ptr2);

    int sblk = NGRP / 2;   // 3125
    for (int step = 0; step < STEPS; ++step) {
        const ushort_t* hin = (step & 1) ? hrowB : hrowA;
        const ushort_t* lin = (step & 1) ? lrowB : lrowA;
        ushort_t* hout      = (step & 1) ? hrowA : hrowB;
        ushort_t* lout      = (step & 1) ? lrowA : lrowB;
        hipLaunchKernelGGL(k_step, dim3(sblk), dim3(512), 0, stream,
                           row_ptr2, adj, hin, lin, hout, lout, BC, be, B2, bg2);
    }
    hipLaunchKernelGGL(k_pool, dim3(G_GRAPHS), dim3(256), 0, stream, n2g, hrowB, lrowB, hg);
    hipLaunchKernelGGL(k_cls, dim3(G_GRAPHS), dim3(64), 0, stream, hg, W1, b1, W2, b2, out);
}